// Round 3
// baseline (378.700 us; speedup 1.0000x reference)
//
#include <hip/hip_runtime.h>
#include <hip/hip_bf16.h>
#include <cstdint>
#include <cstddef>

// Problem constants (fixed by the reference)
#define B_   8
#define N_   4096
#define D_   256
#define E_   32768
#define H_   4
#define C_   64
#define HC_  256
#define ROWS_ (B_*N_)        // 32768
#define NEGSLOPE_ 0.2f

#define NEG_INF_ (-3.402823e38f)

__device__ __forceinline__ float lrelu(float v) { return v >= 0.f ? v : NEGSLOPE_ * v; }

// ---------------------------------------------------------------------------
// K0a: u_h[d] = sum_c W_K[h*64+c, d] * att_r[h,c];  c_h = sum_c b_K*att_r
// grid 4 (h), block 256 (d)
__global__ void k_prep_u(const float* __restrict__ W_K, const float* __restrict__ b_K,
                         const float* __restrict__ att_r,
                         float* __restrict__ u, float* __restrict__ cvec) {
    int h = blockIdx.x;
    int d = threadIdx.x;
    float s = 0.f;
#pragma unroll 8
    for (int c = 0; c < 64; ++c)
        s += W_K[(size_t)(h*64 + c)*256 + d] * att_r[h*64 + c];
    u[h*256 + d] = s;
    if (d == 0) {
        float cs = 0.f;
        for (int c = 0; c < 64; ++c) cs += b_K[h*64 + c] * att_r[h*64 + c];
        cvec[h] = cs;
    }
}

// ---------------------------------------------------------------------------
// K0b: transpose three 256x256 weight matrices (row-major (out,in) -> (in,out))
// grid (8,8,3), block 256
__global__ void k_transpose3(const float* __restrict__ W_V, const float* __restrict__ W1,
                             const float* __restrict__ W2,
                             float* __restrict__ WtV, float* __restrict__ Wt1,
                             float* __restrict__ Wt2) {
    const float* src; float* dst;
    switch (blockIdx.z) {
        case 0:  src = W_V; dst = WtV; break;
        case 1:  src = W1;  dst = Wt1; break;
        default: src = W2;  dst = Wt2; break;
    }
    __shared__ float tile[32][33];
    int tx = threadIdx.x & 31, ty = threadIdx.x >> 5;
    int c0 = blockIdx.x * 32, r0 = blockIdx.y * 32;
#pragma unroll
    for (int i = 0; i < 4; ++i)
        tile[ty + i*8][tx] = src[(size_t)(r0 + ty + i*8)*256 + c0 + tx];
    __syncthreads();
#pragma unroll
    for (int i = 0; i < 4; ++i)
        dst[(size_t)(c0 + ty + i*8)*256 + r0 + tx] = tile[tx][ty + i*8];
}

// ---------------------------------------------------------------------------
// K1: alpha[b,n,h] = lrelu( dot(x[b,n,:], u_h) + c_h )   (lrelu pre-applied: it
// is applied per (b,src,h) identically for every edge in the reference)
// one wave per row; block = 4 waves; grid = ROWS_/4
__global__ void k_alpha(const float* __restrict__ x, const float* __restrict__ u,
                        const float* __restrict__ cvec, float* __restrict__ alpha) {
    int wave = threadIdx.x >> 6, lane = threadIdx.x & 63;
    size_t row = (size_t)blockIdx.x * 4 + wave;
    const float4* x4 = (const float4*)(x + row*256);
    float4 xv = x4[lane];
    const float4* u4 = (const float4*)u;
    float res[4];
#pragma unroll
    for (int h = 0; h < 4; ++h) {
        float4 uv = u4[h*64 + lane];
        float p = xv.x*uv.x + xv.y*uv.y + xv.z*uv.z + xv.w*uv.w;
#pragma unroll
        for (int o = 32; o >= 1; o >>= 1) p += __shfl_xor(p, o);
        res[h] = p;
    }
    if (lane == 0) {
        float4 cv = *(const float4*)cvec;
        float4 o;
        o.x = lrelu(res[0] + cv.x);
        o.y = lrelu(res[1] + cv.y);
        o.z = lrelu(res[2] + cv.z);
        o.w = lrelu(res[3] + cv.w);
        *(float4*)(alpha + row*4) = o;
    }
}

// ---------------------------------------------------------------------------
// K3a: histogram of dst
__global__ void k_hist(const int* __restrict__ ei, int* __restrict__ counts) {
    int e = blockIdx.x * 256 + threadIdx.x;
    if (e < E_) atomicAdd(&counts[ei[E_ + e]], 1);
}

// K3b: exclusive scan of counts[4096] -> offsets[4097]; single block, 256 thr
__global__ void k_scan(const int* __restrict__ counts, int* __restrict__ offsets) {
    __shared__ int tot[256];
    int t = threadIdx.x;
    int local[16];
    int s = 0;
#pragma unroll
    for (int i = 0; i < 16; ++i) { local[i] = s; s += counts[t*16 + i]; }
    tot[t] = s;
    __syncthreads();
    for (int d = 1; d < 256; d <<= 1) {
        int v = (t >= d) ? tot[t - d] : 0;
        __syncthreads();
        tot[t] += v;
        __syncthreads();
    }
    int base = (t == 0) ? 0 : tot[t - 1];
#pragma unroll
    for (int i = 0; i < 16; ++i) offsets[t*16 + i] = base + local[i];
    if (t == 255) offsets[4096] = tot[255];
}

// K3c: scatter src ids into dst buckets
__global__ void k_fill(const int* __restrict__ ei, const int* __restrict__ offsets,
                       int* __restrict__ cursor, int* __restrict__ bucket_src) {
    int e = blockIdx.x * 256 + threadIdx.x;
    if (e >= E_) return;
    int d = ei[E_ + e], srcn = ei[e];
    int pos = atomicAdd(&cursor[d], 1);
    bucket_src[offsets[d] + pos] = srcn;
}

// ---------------------------------------------------------------------------
// K4: per (dst n, batch b): online softmax over incoming edges + weighted
// gather of xV rows + att_r add + LayerNorm0. Wave w owns head h=w; lane = c.
// grid (N_, B_), block 256
__global__ void k_agg_ln0(const float* __restrict__ alpha, const float* __restrict__ xV,
                          const int* __restrict__ offsets, const int* __restrict__ bucket_src,
                          const float* __restrict__ att_r,
                          const float* __restrict__ g0, const float* __restrict__ b0,
                          float* __restrict__ out0) {
    int n = blockIdx.x, b = blockIdx.y;
    int t = threadIdx.x, h = t >> 6, lane = t & 63;
    int beg = offsets[n], end = offsets[n + 1];

    float m = NEG_INF_, den = 0.f, acc = 0.f;
    __shared__ int   s_src[64];
    __shared__ float s_w[64][4];

    for (int chunk = beg; chunk < end; chunk += 64) {
        int cnt = min(64, end - chunk);
        __syncthreads();                       // protect s_src/s_w reuse
        if (t < cnt) s_src[t] = bucket_src[chunk + t];
        __syncthreads();

        float a = NEG_INF_;
        if (lane < cnt) a = alpha[((size_t)b*N_ + s_src[lane])*4 + h];
        float mc = a;
#pragma unroll
        for (int o = 32; o >= 1; o >>= 1) mc = fmaxf(mc, __shfl_xor(mc, o));
        float m_new = fmaxf(m, mc);
        float ex = (lane < cnt) ? __expf(a - m_new) : 0.f;
        float ss = ex;
#pragma unroll
        for (int o = 32; o >= 1; o >>= 1) ss += __shfl_xor(ss, o);
        float r = __expf(m - m_new);           // 0 when m was -inf
        den = den * r + ss;
        acc *= r;
        m = m_new;
        s_w[lane][h] = ex;
        __syncthreads();

        for (int e = 0; e < cnt; ++e) {
            float w = s_w[e][h];
            acc += w * xV[((size_t)b*N_ + s_src[e])*256 + h*64 + lane];
        }
    }

    float outv = acc / (den + 1e-16f) + att_r[t];

    // LayerNorm0 across the 256-wide row held by this block
    float s1 = outv, s2 = outv * outv;
#pragma unroll
    for (int o = 32; o >= 1; o >>= 1) { s1 += __shfl_xor(s1, o); s2 += __shfl_xor(s2, o); }
    __shared__ float red[8];
    if (lane == 0) { red[h] = s1; red[4 + h] = s2; }
    __syncthreads();
    float mean = (red[0] + red[1] + red[2] + red[3]) * (1.f/256.f);
    float msq  = (red[4] + red[5] + red[6] + red[7]) * (1.f/256.f);
    float inv = rsqrtf(msq - mean*mean + 1e-5f);
    out0[((size_t)b*N_ + n)*256 + t] = (outv - mean) * inv * g0[t] + b0[t];
}

// ---------------------------------------------------------------------------
// GEMM: out[M=32768, 256] = A[M,256] @ Wt[256,256] (+bias, +epilogue)
// MODE 0: out = acc+bias            (xV)
// MODE 1: out = relu(acc+bias)      (h)
// MODE 2: y = res + relu(acc+bias); out = LayerNorm1(y)   (final)
// NOTE: in MODE 2 `res` and `out` ALIAS (d_out) — no __restrict__ on them.
// BM=64, BN=256(full), BK=16; block 256 thr; each thread 8x8 outputs.
template<int MODE>
__global__ __launch_bounds__(256) void k_gemm(const float* __restrict__ A,
                                              const float* __restrict__ Wt,
                                              const float* __restrict__ bias,
                                              const float* res,
                                              const float* __restrict__ g,
                                              const float* __restrict__ bvec,
                                              float* out) {
    __shared__ float As[64][16];
    __shared__ float Bs[16][256];
    int t = threadIdx.x;
    int tx = t & 31, ty = t >> 5;
    size_t m0 = (size_t)blockIdx.x * 64;

    float acc[8][8];
#pragma unroll
    for (int r = 0; r < 8; ++r)
#pragma unroll
        for (int j = 0; j < 8; ++j) acc[r][j] = 0.f;

    for (int k0 = 0; k0 < 256; k0 += 16) {
        __syncthreads();
        {   // As: 64x16, 4 floats per thread
            int row = t >> 2, col = (t & 3) * 4;
            *(float4*)&As[row][col] = *(const float4*)&A[(m0 + row)*256 + k0 + col];
        }
        {   // Bs: 16x256, 16 floats per thread
            int kk = t >> 4, c0 = (t & 15) * 16;
            const float4* sp = (const float4*)&Wt[(size_t)(k0 + kk)*256 + c0];
            float4* dp = (float4*)&Bs[kk][c0];
            dp[0] = sp[0]; dp[1] = sp[1]; dp[2] = sp[2]; dp[3] = sp[3];
        }
        __syncthreads();
#pragma unroll
        for (int kk = 0; kk < 16; ++kk) {
            float a[8], bb[8];
#pragma unroll
            for (int r = 0; r < 8; ++r) a[r] = As[ty*8 + r][kk];
#pragma unroll
            for (int j = 0; j < 8; ++j) bb[j] = Bs[kk][tx*8 + j];
#pragma unroll
            for (int r = 0; r < 8; ++r)
#pragma unroll
                for (int j = 0; j < 8; ++j) acc[r][j] += a[r] * bb[j];
        }
    }

#pragma unroll
    for (int r = 0; r < 8; ++r) {
        size_t mrow = m0 + ty*8 + r;
        float y[8];
#pragma unroll
        for (int j = 0; j < 8; ++j) {
            int col = tx*8 + j;
            float v = acc[r][j] + bias[col];
            if (MODE == 0) y[j] = v;
            if (MODE == 1) y[j] = fmaxf(v, 0.f);
            if (MODE == 2) y[j] = res[mrow*256 + col] + fmaxf(v, 0.f);
        }
        if (MODE < 2) {
            *(float4*)&out[mrow*256 + tx*8]     = make_float4(y[0], y[1], y[2], y[3]);
            *(float4*)&out[mrow*256 + tx*8 + 4] = make_float4(y[4], y[5], y[6], y[7]);
        } else {
            float s1 = 0.f, s2 = 0.f;
#pragma unroll
            for (int j = 0; j < 8; ++j) { s1 += y[j]; s2 += y[j]*y[j]; }
#pragma unroll
            for (int o = 16; o >= 1; o >>= 1) { s1 += __shfl_xor(s1, o); s2 += __shfl_xor(s2, o); }
            float mean = s1 * (1.f/256.f), msq = s2 * (1.f/256.f);
            float inv = rsqrtf(msq - mean*mean + 1e-5f);
            float o0[4], o1[4];
#pragma unroll
            for (int j = 0; j < 8; ++j) {
                int col = tx*8 + j;
                float vv = (y[j] - mean) * inv * g[col] + bvec[col];
                if (j < 4) o0[j] = vv; else o1[j - 4] = vv;
            }
            *(float4*)&out[mrow*256 + tx*8]     = make_float4(o0[0], o0[1], o0[2], o0[3]);
            *(float4*)&out[mrow*256 + tx*8 + 4] = make_float4(o1[0], o1[1], o1[2], o1[3]);
        }
    }
}

// ---------------------------------------------------------------------------
extern "C" void kernel_launch(void* const* d_in, const int* in_sizes, int n_in,
                              void* d_out, int out_size, void* d_ws, size_t ws_size,
                              hipStream_t stream) {
    const float* x     = (const float*)d_in[0];
    const int*   ei    = (const int*)  d_in[1];
    const float* W_K   = (const float*)d_in[2];
    const float* b_K   = (const float*)d_in[3];
    const float* W_V   = (const float*)d_in[4];
    const float* b_V   = (const float*)d_in[5];
    const float* att_r = (const float*)d_in[6];
    const float* ln0_g = (const float*)d_in[7];
    const float* ln0_b = (const float*)d_in[8];
    const float* ln1_g = (const float*)d_in[9];
    const float* ln1_b = (const float*)d_in[10];
    const float* W1    = (const float*)d_in[11];
    const float* b1    = (const float*)d_in[12];
    const float* W2    = (const float*)d_in[13];
    const float* b2    = (const float*)d_in[14];
    float* out = (float*)d_out;

    // workspace layout (floats). out0 lives in d_out (each final element is
    // read-then-written by the same thread in k_gemm<2>, so aliasing is safe).
    float* ws    = (float*)d_ws;
    float* u     = ws;                      // 1024
    float* cvec  = ws + 1024;               // 4 (padded to 1024)
    float* alpha = ws + 2048;               // 131072
    float* xV    = ws + 2048 + 131072;      // 8388608 (reused as hbuf after K4)
    float* WtV   = xV + 8388608;            // 65536
    float* Wt1   = WtV + 65536;             // 65536
    float* Wt2   = Wt1 + 65536;             // 65536
    int*   ints  = (int*)(Wt2 + 65536);
    int* counts  = ints;                    // 4096
    int* cursor  = ints + 4096;             // 4096
    int* offsets = ints + 8192;             // 4097 (padded to 4352)
    int* bucket  = ints + 12544;            // 32768
    float* out0  = out;                     // alias d_out
    float* hbuf  = xV;                      // alias xV (dead after K4)

    // Guard: required workspace bytes. If the harness gave us less, bail out
    // cleanly (correctness fails with a readable absmax, no OOB corruption).
    size_t need = (size_t)(2048 + 131072 + 8388608 + 3*65536) * sizeof(float)
                + (size_t)(12544 + 32768) * sizeof(int);
    if (ws_size < need) return;

    hipMemsetAsync(counts, 0, 8192 * sizeof(int), stream);   // counts + cursor

    k_prep_u   <<<4, 256, 0, stream>>>(W_K, b_K, att_r, u, cvec);
    k_transpose3<<<dim3(8, 8, 3), 256, 0, stream>>>(W_V, W1, W2, WtV, Wt1, Wt2);
    k_alpha    <<<ROWS_/4, 256, 0, stream>>>(x, u, cvec, alpha);
    k_gemm<0>  <<<ROWS_/64, 256, 0, stream>>>(x, WtV, b_V, nullptr, nullptr, nullptr, xV);
    k_hist     <<<E_/256, 256, 0, stream>>>(ei, counts);
    k_scan     <<<1, 256, 0, stream>>>(counts, offsets);
    k_fill     <<<E_/256, 256, 0, stream>>>(ei, offsets, cursor, bucket);
    k_agg_ln0  <<<dim3(N_, B_), 256, 0, stream>>>(alpha, xV, offsets, bucket,
                                                  att_r, ln0_g, ln0_b, out0);
    k_gemm<1>  <<<ROWS_/64, 256, 0, stream>>>(out0, Wt1, b1, nullptr, nullptr, nullptr, hbuf);
    k_gemm<2>  <<<ROWS_/64, 256, 0, stream>>>(hbuf, Wt2, b2, out0, ln1_g, ln1_b, out);
}

// Round 5
// 240.682 us; speedup vs baseline: 1.5734x; 1.5734x over previous
//
#include <hip/hip_runtime.h>
#include <hip/hip_bf16.h>
#include <cstdint>
#include <cstddef>

// Problem constants (fixed by the reference)
#define B_   8
#define N_   4096
#define E_   32768
#define ROWS_ 32768          // B_*N_
#define NEGSLOPE_ 0.2f
#define NEG_INF_ (-3.402823e38f)

typedef __attribute__((ext_vector_type(8))) __bf16 bf16x8;
typedef __attribute__((ext_vector_type(4))) float  f32x4;

__device__ __forceinline__ float lrelu(float v) { return v >= 0.f ? v : NEGSLOPE_ * v; }

__device__ __forceinline__ float bf2f(ushort u) {
    union { uint32_t i; float f; } c; c.i = ((uint32_t)u) << 16; return c.f;
}
__device__ __forceinline__ ushort f2bf(float f) {
    __hip_bfloat16 h = __float2bfloat16(f);          // RNE
    return *reinterpret_cast<ushort*>(&h);
}

// ---------------------------------------------------------------------------
// K0a: u_h[d] = sum_c W_K[h*64+c, d] * att_r[h,c];  c_h = sum_c b_K*att_r
__global__ void k_prep_u(const float* __restrict__ W_K, const float* __restrict__ b_K,
                         const float* __restrict__ att_r,
                         float* __restrict__ u, float* __restrict__ cvec) {
    int h = blockIdx.x;
    int d = threadIdx.x;
    float s = 0.f;
#pragma unroll 8
    for (int c = 0; c < 64; ++c)
        s += W_K[(size_t)(h*64 + c)*256 + d] * att_r[h*64 + c];
    u[h*256 + d] = s;
    if (d == 0) {
        float cs = 0.f;
        for (int c = 0; c < 64; ++c) cs += b_K[h*64 + c] * att_r[h*64 + c];
        cvec[h] = cs;
    }
}

// ---------------------------------------------------------------------------
// K0b: convert the three 256x256 weight matrices to bf16 (keep [n][k] layout —
// it is exactly the B-operand layout the MFMA fragment wants; no transpose).
__global__ void k_cvtW(const float* __restrict__ W_V, const float* __restrict__ W1,
                       const float* __restrict__ W2,
                       ushort* __restrict__ WVb, ushort* __restrict__ W1b,
                       ushort* __restrict__ W2b) {
    const float* s; ushort* d;
    switch (blockIdx.y) {
        case 0:  s = W_V; d = WVb; break;
        case 1:  s = W1;  d = W1b; break;
        default: s = W2;  d = W2b; break;
    }
    int i = blockIdx.x * 1024 + threadIdx.x * 4;
    float4 v = *(const float4*)&s[i];
    ushort4 o; o.x = f2bf(v.x); o.y = f2bf(v.y); o.z = f2bf(v.z); o.w = f2bf(v.w);
    *(ushort4*)&d[i] = o;
}

// ---------------------------------------------------------------------------
// K1: alpha[b,n,h] = lrelu(dot(x[row], u_h) + c_h); also emits x in bf16.
// one wave per row; block = 4 waves; grid = ROWS_/4
__global__ void k_alpha(const float* __restrict__ x, const float* __restrict__ u,
                        const float* __restrict__ cvec, float* __restrict__ alpha,
                        ushort* __restrict__ xb) {
    int wave = threadIdx.x >> 6, lane = threadIdx.x & 63;
    size_t row = (size_t)blockIdx.x * 4 + wave;
    const float4* x4 = (const float4*)(x + row*256);
    float4 xv = x4[lane];
    // bf16 copy of x (read-once fusion)
    ushort4 xw; xw.x = f2bf(xv.x); xw.y = f2bf(xv.y); xw.z = f2bf(xv.z); xw.w = f2bf(xv.w);
    *(ushort4*)&xb[row*256 + lane*4] = xw;

    const float4* u4 = (const float4*)u;
    float res[4];
#pragma unroll
    for (int h = 0; h < 4; ++h) {
        float4 uv = u4[h*64 + lane];
        float p = xv.x*uv.x + xv.y*uv.y + xv.z*uv.z + xv.w*uv.w;
#pragma unroll
        for (int o = 32; o >= 1; o >>= 1) p += __shfl_xor(p, o);
        res[h] = p;
    }
    if (lane == 0) {
        float4 cv = *(const float4*)cvec;
        float4 o;
        o.x = lrelu(res[0] + cv.x);
        o.y = lrelu(res[1] + cv.y);
        o.z = lrelu(res[2] + cv.z);
        o.w = lrelu(res[3] + cv.w);
        *(float4*)(alpha + row*4) = o;
    }
}

// ---------------------------------------------------------------------------
// CSR build: histogram / scan / fill
__global__ void k_hist(const int* __restrict__ ei, int* __restrict__ counts) {
    int e = blockIdx.x * 256 + threadIdx.x;
    if (e < E_) atomicAdd(&counts[ei[E_ + e]], 1);
}

__global__ void k_scan(const int* __restrict__ counts, int* __restrict__ offsets) {
    __shared__ int tot[256];
    int t = threadIdx.x;
    int local[16];
    int s = 0;
#pragma unroll
    for (int i = 0; i < 16; ++i) { local[i] = s; s += counts[t*16 + i]; }
    tot[t] = s;
    __syncthreads();
    for (int d = 1; d < 256; d <<= 1) {
        int v = (t >= d) ? tot[t - d] : 0;
        __syncthreads();
        tot[t] += v;
        __syncthreads();
    }
    int base = (t == 0) ? 0 : tot[t - 1];
#pragma unroll
    for (int i = 0; i < 16; ++i) offsets[t*16 + i] = base + local[i];
    if (t == 255) offsets[4096] = tot[255];
}

__global__ void k_fill(const int* __restrict__ ei, const int* __restrict__ offsets,
                       int* __restrict__ cursor, int* __restrict__ bucket_src) {
    int e = blockIdx.x * 256 + threadIdx.x;
    if (e >= E_) return;
    int d = ei[E_ + e], srcn = ei[e];
    int pos = atomicAdd(&cursor[d], 1);
    bucket_src[offsets[d] + pos] = srcn;
}

// ---------------------------------------------------------------------------
// K4: per (dst n, batch b): online softmax over incoming edges + weighted
// gather of xV(bf16) rows + att_r add + LayerNorm0 -> out0 (bf16).
__global__ void k_agg_ln0(const float* __restrict__ alpha, const ushort* __restrict__ xVb,
                          const int* __restrict__ offsets, const int* __restrict__ bucket_src,
                          const float* __restrict__ att_r,
                          const float* __restrict__ g0, const float* __restrict__ b0,
                          ushort* __restrict__ out0b) {
    int n = blockIdx.x, b = blockIdx.y;
    int t = threadIdx.x, h = t >> 6, lane = t & 63;
    int beg = offsets[n], end = offsets[n + 1];

    float m = NEG_INF_, den = 0.f, acc = 0.f;
    __shared__ int   s_src[64];
    __shared__ float s_w[64][4];

    for (int chunk = beg; chunk < end; chunk += 64) {
        int cnt = min(64, end - chunk);
        __syncthreads();
        if (t < cnt) s_src[t] = bucket_src[chunk + t];
        __syncthreads();

        float a = NEG_INF_;
        if (lane < cnt) a = alpha[((size_t)b*N_ + s_src[lane])*4 + h];
        float mc = a;
#pragma unroll
        for (int o = 32; o >= 1; o >>= 1) mc = fmaxf(mc, __shfl_xor(mc, o));
        float m_new = fmaxf(m, mc);
        float ex = (lane < cnt) ? __expf(a - m_new) : 0.f;
        float ss = ex;
#pragma unroll
        for (int o = 32; o >= 1; o >>= 1) ss += __shfl_xor(ss, o);
        float r = __expf(m - m_new);
        den = den * r + ss;
        acc *= r;
        m = m_new;
        s_w[lane][h] = ex;
        __syncthreads();

        for (int e = 0; e < cnt; ++e) {
            float w = s_w[e][h];
            acc += w * bf2f(xVb[((size_t)b*N_ + s_src[e])*256 + h*64 + lane]);
        }
    }

    float outv = acc / (den + 1e-16f) + att_r[t];

    float s1 = outv, s2 = outv * outv;
#pragma unroll
    for (int o = 32; o >= 1; o >>= 1) { s1 += __shfl_xor(s1, o); s2 += __shfl_xor(s2, o); }
    __shared__ float red[8];
    if (lane == 0) { red[h] = s1; red[4 + h] = s2; }
    __syncthreads();
    float mean = (red[0] + red[1] + red[2] + red[3]) * (1.f/256.f);
    float msq  = (red[4] + red[5] + red[6] + red[7]) * (1.f/256.f);
    float inv = rsqrtf(msq - mean*mean + 1e-5f);
    out0b[((size_t)b*N_ + n)*256 + t] = f2bf((outv - mean) * inv * g0[t] + b0[t]);
}

// ---------------------------------------------------------------------------
// MFMA GEMM: out[M=32768, 256] = A_bf16[M,256] @ W_bf16[n][k]^T (+bias, epilogue)
// MODE 0: out_bf16 = acc+bias                      (xV; out may ALIAS A in-place:
//         block reads only its own 64 A-rows, writes same rows post-loop)
// MODE 1: out_bf16 = relu(acc+bias)                (h)
// MODE 2: y = bf2f(res) + relu(acc+bias); out_f32 = LayerNorm1(y)
// BM=64, BN=256 (full row -> LN fits in-block), BK=32, 8 K-steps, 4 waves.
// Staging: global_load_lds 16B, XOR chunk-swizzle on the GLOBAL source,
// matching swizzle on the LDS fragment read (bank-balanced: 8 lanes/window).
template<int MODE>
__global__ __launch_bounds__(256) void k_mgemm(const ushort* __restrict__ A,
                                               const ushort* __restrict__ Bw,
                                               const float* __restrict__ bias,
                                               const ushort* __restrict__ res,
                                               const float* __restrict__ g,
                                               const float* __restrict__ bvec,
                                               void* __restrict__ outp) {
    __shared__ __align__(16) ushort As[64*32];      // [row][k] 4KB
    __shared__ __align__(16) ushort Bs[256*32];     // [n][k] 16KB
    __shared__ float2 red[64][4];                   // MODE2 row partials

    int t = threadIdx.x;
    int w = t >> 6, lane = t & 63;
    int fr = lane & 15, fg = lane >> 4;
    size_t m0 = (size_t)blockIdx.x * 64;

    // staging geometry: thread t owns LDS chunk t (16B), source chunk swizzled
    int srow = t >> 2;                         // 0..63
    int schunk = (t & 3) ^ (srow & 3);         // inverse swizzle on source
    const ushort* gA  = A  + (m0 + srow)*256 + schunk*8;
    const ushort* gB0 = Bw + (size_t)srow*256 + schunk*8;

    // fragment read offsets (swizzled chunk)
    int chnk = (fg ^ (fr & 3)) * 8;

    f32x4 acc[4][4];
#pragma unroll
    for (int mt = 0; mt < 4; ++mt)
#pragma unroll
        for (int nt = 0; nt < 4; ++nt) acc[mt][nt] = (f32x4){0.f, 0.f, 0.f, 0.f};

    for (int ks = 0; ks < 8; ++ks) {
        int k0 = ks * 32;
        __builtin_amdgcn_global_load_lds(
            (const __attribute__((address_space(1))) void*)(gA + k0),
            (__attribute__((address_space(3))) void*)(&As[t*8]), 16, 0, 0);
#pragma unroll
        for (int rr = 0; rr < 4; ++rr)
            __builtin_amdgcn_global_load_lds(
                (const __attribute__((address_space(1))) void*)(gB0 + rr*16384 + k0),
                (__attribute__((address_space(3))) void*)(&Bs[rr*2048 + t*8]), 16, 0, 0);
        __syncthreads();

        bf16x8 a[4], b[4];
#pragma unroll
        for (int mt = 0; mt < 4; ++mt)
            a[mt] = *(const bf16x8*)&As[(mt*16 + fr)*32 + chnk];
#pragma unroll
        for (int nt = 0; nt < 4; ++nt)
            b[nt] = *(const bf16x8*)&Bs[(w*64 + nt*16 + fr)*32 + chnk];
#pragma unroll
        for (int mt = 0; mt < 4; ++mt)
#pragma unroll
            for (int nt = 0; nt < 4; ++nt)
                acc[mt][nt] = __builtin_amdgcn_mfma_f32_16x16x32_bf16(
                    a[mt], b[nt], acc[mt][nt], 0, 0, 0);
        __syncthreads();
    }

    // epilogue: C layout col = lane&15 (+nt*16+w*64), row = fg*4+j (+mt*16)
    int colb = w*64 + fr;
    float biasv[4];
#pragma unroll
    for (int nt = 0; nt < 4; ++nt) biasv[nt] = bias[colb + nt*16];

    if (MODE < 2) {
        ushort* ob = (ushort*)outp;
#pragma unroll
        for (int mt = 0; mt < 4; ++mt)
#pragma unroll
            for (int j = 0; j < 4; ++j) {
                int row = mt*16 + fg*4 + j;
#pragma unroll
                for (int nt = 0; nt < 4; ++nt) {
                    float v = acc[mt][nt][j] + biasv[nt];
                    if (MODE == 1) v = fmaxf(v, 0.f);
                    ob[(m0 + row)*256 + colb + nt*16] = f2bf(v);
                }
            }
    } else {
        float gv[4], bvv[4];
#pragma unroll
        for (int nt = 0; nt < 4; ++nt) { gv[nt] = g[colb + nt*16]; bvv[nt] = bvec[colb + nt*16]; }
#pragma unroll
        for (int mt = 0; mt < 4; ++mt)
#pragma unroll
            for (int j = 0; j < 4; ++j) {
                int row = mt*16 + fg*4 + j;
                float p1 = 0.f, p2 = 0.f;
#pragma unroll
                for (int nt = 0; nt < 4; ++nt) {
                    float v = acc[mt][nt][j] + biasv[nt];
                    float y = bf2f(res[(m0 + row)*256 + colb + nt*16]) + fmaxf(v, 0.f);
                    acc[mt][nt][j] = y;
                    p1 += y; p2 += y*y;
                }
#pragma unroll
                for (int o = 8; o >= 1; o >>= 1) { p1 += __shfl_xor(p1, o); p2 += __shfl_xor(p2, o); }
                if (fr == 0) red[row][w] = make_float2(p1, p2);
            }
        __syncthreads();
        float* of = (float*)outp;
#pragma unroll
        for (int mt = 0; mt < 4; ++mt)
#pragma unroll
            for (int j = 0; j < 4; ++j) {
                int row = mt*16 + fg*4 + j;
                float2 s0 = red[row][0], sA = red[row][1], sB = red[row][2], sC = red[row][3];
                float s = s0.x + sA.x + sB.x + sC.x;
                float q = s0.y + sA.y + sB.y + sC.y;
                float mean = s * (1.f/256.f);
                float inv = rsqrtf(q * (1.f/256.f) - mean*mean + 1e-5f);
#pragma unroll
                for (int nt = 0; nt < 4; ++nt)
                    of[(m0 + row)*256 + colb + nt*16] =
                        (acc[mt][nt][j] - mean) * inv * gv[nt] + bvv[nt];
            }
    }
}

// ---------------------------------------------------------------------------
extern "C" void kernel_launch(void* const* d_in, const int* in_sizes, int n_in,
                              void* d_out, int out_size, void* d_ws, size_t ws_size,
                              hipStream_t stream) {
    const float* x     = (const float*)d_in[0];
    const int*   ei    = (const int*)  d_in[1];
    const float* W_K   = (const float*)d_in[2];
    const float* b_K   = (const float*)d_in[3];
    const float* W_V   = (const float*)d_in[4];
    const float* b_V   = (const float*)d_in[5];
    const float* att_r = (const float*)d_in[6];
    const float* ln0_g = (const float*)d_in[7];
    const float* ln0_b = (const float*)d_in[8];
    const float* ln1_g = (const float*)d_in[9];
    const float* ln1_b = (const float*)d_in[10];
    const float* W1    = (const float*)d_in[11];
    const float* b1    = (const float*)d_in[12];
    const float* W2    = (const float*)d_in[13];
    const float* b2    = (const float*)d_in[14];
    float* out = (float*)d_out;

    // workspace layout (bytes). Aliasing plan (all safe, argued per-kernel):
    //   bufA: x_bf16 -> (GEMM0 in-place) xV_bf16 -> (after agg) h_bf16
    //   bufB: out0_bf16 (lives until GEMM2 residual read)
    char* wsb = (char*)d_ws;
    float*  u     = (float*) (wsb);                 // 4KB
    float*  cvec  = (float*) (wsb + 4096);          // 4 floats (pad 4KB)
    float*  alpha = (float*) (wsb + 8192);          // 512KB
    ushort* WVb   = (ushort*)(wsb + 532480);        // 128KB
    ushort* W1b   = WVb + 65536;                    // 128KB
    ushort* W2b   = W1b + 65536;                    // 128KB
    int*    ints  = (int*)  (W2b + 65536);
    int* counts   = ints;                           // 4096
    int* cursor   = ints + 4096;                    // 4096
    int* offsets  = ints + 8192;                    // 4097 (pad)
    int* bucket   = ints + 12544;                   // 32768
    ushort* bufA  = (ushort*)(wsb + 1114112);       // 16MB
    ushort* bufB  = bufA + 8388608;                 // 16MB
    size_t need   = 1114112 + 2ull*16777216;        // ~33.1 MB (< proven 35.1)

    if (ws_size < need) return;   // clean fail (visible absmax), no OOB

    hipMemsetAsync(counts, 0, 8192 * sizeof(int), stream);   // counts + cursor

    k_prep_u <<<4, 256, 0, stream>>>(W_K, b_K, att_r, u, cvec);
    k_cvtW   <<<dim3(64, 3), 256, 0, stream>>>(W_V, W1, W2, WVb, W1b, W2b);
    k_alpha  <<<ROWS_/4, 256, 0, stream>>>(x, u, cvec, alpha, bufA);
    k_mgemm<0><<<ROWS_/64, 256, 0, stream>>>(bufA, WVb, b_V, nullptr, nullptr, nullptr, bufA);
    k_hist   <<<E_/256, 256, 0, stream>>>(ei, counts);
    k_scan   <<<1, 256, 0, stream>>>(counts, offsets);
    k_fill   <<<E_/256, 256, 0, stream>>>(ei, offsets, cursor, bucket);
    k_agg_ln0<<<dim3(N_, B_), 256, 0, stream>>>(alpha, bufA, offsets, bucket,
                                                att_r, ln0_g, ln0_b, bufB);
    k_mgemm<1><<<ROWS_/64, 256, 0, stream>>>(bufB, W1b, b1, nullptr, nullptr, nullptr, bufA);
    k_mgemm<2><<<ROWS_/64, 256, 0, stream>>>(bufA, W2b, b2, bufB, ln1_g, ln1_b, out);
}

// Round 7
// 213.944 us; speedup vs baseline: 1.7701x; 1.1250x over previous
//
#include <hip/hip_runtime.h>
#include <hip/hip_bf16.h>
#include <cstdint>
#include <cstddef>

// Problem constants (fixed by the reference)
#define B_   8
#define N_   4096
#define E_   32768
#define ROWS_ 32768          // B_*N_
#define NEGSLOPE_ 0.2f
#define NEG_INF_ (-3.402823e38f)

typedef __attribute__((ext_vector_type(8))) __bf16 bf16x8;
typedef __attribute__((ext_vector_type(4))) float  f32x4;

__device__ __forceinline__ float lrelu(float v) { return v >= 0.f ? v : NEGSLOPE_ * v; }

__device__ __forceinline__ float bf2f(ushort u) {
    union { uint32_t i; float f; } c; c.i = ((uint32_t)u) << 16; return c.f;
}
__device__ __forceinline__ ushort f2bf(float f) {
    __hip_bfloat16 h = __float2bfloat16(f);          // RNE
    return *reinterpret_cast<ushort*>(&h);
}

__device__ __forceinline__ float4 wred_max4(float4 v) {
#pragma unroll
    for (int o = 32; o >= 1; o >>= 1) {
        v.x = fmaxf(v.x, __shfl_xor(v.x, o));
        v.y = fmaxf(v.y, __shfl_xor(v.y, o));
        v.z = fmaxf(v.z, __shfl_xor(v.z, o));
        v.w = fmaxf(v.w, __shfl_xor(v.w, o));
    }
    return v;
}
__device__ __forceinline__ float4 wred_sum4(float4 v) {
#pragma unroll
    for (int o = 32; o >= 1; o >>= 1) {
        v.x += __shfl_xor(v.x, o);
        v.y += __shfl_xor(v.y, o);
        v.z += __shfl_xor(v.z, o);
        v.w += __shfl_xor(v.w, o);
    }
    return v;
}

// ---------------------------------------------------------------------------
// K0a: u_h[d] = sum_c W_K[h*64+c, d] * att_r[h,c];  c_h = sum_c b_K*att_r
__global__ void k_prep_u(const float* __restrict__ W_K, const float* __restrict__ b_K,
                         const float* __restrict__ att_r,
                         float* __restrict__ u, float* __restrict__ cvec) {
    int h = blockIdx.x;
    int d = threadIdx.x;
    float s = 0.f;
#pragma unroll 8
    for (int c = 0; c < 64; ++c)
        s += W_K[(size_t)(h*64 + c)*256 + d] * att_r[h*64 + c];
    u[h*256 + d] = s;
    if (d == 0) {
        float cs = 0.f;
        for (int c = 0; c < 64; ++c) cs += b_K[h*64 + c] * att_r[h*64 + c];
        cvec[h] = cs;
    }
}

// ---------------------------------------------------------------------------
// K0b: convert the three 256x256 weight matrices to bf16, [n][k] layout.
// W1 additionally gets the k-permutation  k' = (k&63)*4 + (k>>6)  so that it
// matches out0's c-major storage (GEMM is invariant under a shared k-perm).
__global__ void k_cvtW(const float* __restrict__ W_V, const float* __restrict__ W1,
                       const float* __restrict__ W2,
                       ushort* __restrict__ WVb, ushort* __restrict__ W1b,
                       ushort* __restrict__ W2b) {
    int i = blockIdx.x * 1024 + threadIdx.x * 4;
    if (blockIdx.y == 1) {           // W1: permuted read, coalesced write
        int n = i >> 8, c = (i & 255) >> 2;   // output k' = c*4 + h, h=0..3
        const float* s = W1 + (size_t)n*256 + c;
        ushort4 o;
        o.x = f2bf(s[0]);   // h=0 -> orig k = 0*64 + c
        o.y = f2bf(s[64]);
        o.z = f2bf(s[128]);
        o.w = f2bf(s[192]);
        *(ushort4*)&W1b[i] = o;
    } else {
        const float* s = (blockIdx.y == 0) ? W_V : W2;
        ushort* d      = (blockIdx.y == 0) ? WVb : W2b;
        float4 v = *(const float4*)&s[i];
        ushort4 o; o.x = f2bf(v.x); o.y = f2bf(v.y); o.z = f2bf(v.z); o.w = f2bf(v.w);
        *(ushort4*)&d[i] = o;
    }
}

// ---------------------------------------------------------------------------
// K1: alpha[b,n,h] = lrelu(dot(x[row], u_h) + c_h); also emits x in bf16.
// one wave per row; block = 4 waves; grid = ROWS_/4
__global__ void k_alpha(const float* __restrict__ x, const float* __restrict__ u,
                        const float* __restrict__ cvec, float* __restrict__ alpha,
                        ushort* __restrict__ xb) {
    int wave = threadIdx.x >> 6, lane = threadIdx.x & 63;
    size_t row = (size_t)blockIdx.x * 4 + wave;
    const float4* x4 = (const float4*)(x + row*256);
    float4 xv = x4[lane];
    ushort4 xw; xw.x = f2bf(xv.x); xw.y = f2bf(xv.y); xw.z = f2bf(xv.z); xw.w = f2bf(xv.w);
    *(ushort4*)&xb[row*256 + lane*4] = xw;

    const float4* u4 = (const float4*)u;
    float res[4];
#pragma unroll
    for (int h = 0; h < 4; ++h) {
        float4 uv = u4[h*64 + lane];
        float p = xv.x*uv.x + xv.y*uv.y + xv.z*uv.z + xv.w*uv.w;
#pragma unroll
        for (int o = 32; o >= 1; o >>= 1) p += __shfl_xor(p, o);
        res[h] = p;
    }
    if (lane == 0) {
        float4 cv = *(const float4*)cvec;
        float4 o;
        o.x = lrelu(res[0] + cv.x);
        o.y = lrelu(res[1] + cv.y);
        o.z = lrelu(res[2] + cv.z);
        o.w = lrelu(res[3] + cv.w);
        *(float4*)(alpha + row*4) = o;
    }
}

// ---------------------------------------------------------------------------
// CSR build: histogram / scan / fill
__global__ void k_hist(const int* __restrict__ ei, int* __restrict__ counts) {
    int e = blockIdx.x * 256 + threadIdx.x;
    if (e < E_) atomicAdd(&counts[ei[E_ + e]], 1);
}

__global__ void k_scan(const int* __restrict__ counts, int* __restrict__ offsets) {
    __shared__ int tot[256];
    int t = threadIdx.x;
    int local[16];
    int s = 0;
#pragma unroll
    for (int i = 0; i < 16; ++i) { local[i] = s; s += counts[t*16 + i]; }
    tot[t] = s;
    __syncthreads();
    for (int d = 1; d < 256; d <<= 1) {
        int v = (t >= d) ? tot[t - d] : 0;
        __syncthreads();
        tot[t] += v;
        __syncthreads();
    }
    int base = (t == 0) ? 0 : tot[t - 1];
#pragma unroll
    for (int i = 0; i < 16; ++i) offsets[t*16 + i] = base + local[i];
    if (t == 255) offsets[4096] = tot[255];
}

__global__ void k_fill(const int* __restrict__ ei, const int* __restrict__ offsets,
                       int* __restrict__ cursor, int* __restrict__ bucket_src) {
    int e = blockIdx.x * 256 + threadIdx.x;
    if (e >= E_) return;
    int d = ei[E_ + e], srcn = ei[e];
    int pos = atomicAdd(&cursor[d], 1);
    bucket_src[offsets[d] + pos] = srcn;
}

// ---------------------------------------------------------------------------
// K4: ONE WAVE per (n,b) pair. xV is stored c-major [row][c*4+h], so lane
// (=channel c) reads ushort4 = all 4 heads per edge (512 B/wave, coalesced).
// Online softmax per wave (float4 over heads), weights broadcast through
// wave-private LDS; gather unrolled x4 (weights past cnt are 0). No
// __syncthreads. Epilogue: att_r + LN0, output c-major bf16.
__global__ __launch_bounds__(256) void k_agg_ln0(
        const float* __restrict__ alpha, const ushort* __restrict__ xVb,
        const int* __restrict__ offsets, const int* __restrict__ bucket_src,
        const float* __restrict__ att_r,
        const float* __restrict__ g0, const float* __restrict__ b0,
        ushort* __restrict__ out0b) {
    __shared__ float4 s_w4[4][64];
    int t = threadIdx.x, wv = t >> 6, lane = t & 63;
    int gp = blockIdx.x * 4 + wv;           // 0..32767
    int n = gp >> 3, b = gp & 7;
    int beg = offsets[n], end = offsets[n + 1];
    size_t brow = (size_t)b * N_;

    float4 m4   = make_float4(NEG_INF_, NEG_INF_, NEG_INF_, NEG_INF_);
    float4 den4 = make_float4(0.f, 0.f, 0.f, 0.f);
    float4 acc4 = make_float4(0.f, 0.f, 0.f, 0.f);

    for (int chunk = beg; chunk < end; chunk += 64) {
        int cnt = min(64, end - chunk);
        int my_src = (lane < cnt) ? bucket_src[chunk + lane] : 0;
        float4 a4 = make_float4(NEG_INF_, NEG_INF_, NEG_INF_, NEG_INF_);
        if (lane < cnt) a4 = *(const float4*)&alpha[(brow + my_src)*4];

        float4 mc = wred_max4(a4);
        float4 mn;
        mn.x = fmaxf(m4.x, mc.x); mn.y = fmaxf(m4.y, mc.y);
        mn.z = fmaxf(m4.z, mc.z); mn.w = fmaxf(m4.w, mc.w);
        float4 ex;                               // lanes >= cnt: exp(-inf)=0
        ex.x = __expf(a4.x - mn.x); ex.y = __expf(a4.y - mn.y);
        ex.z = __expf(a4.z - mn.z); ex.w = __expf(a4.w - mn.w);
        float4 ss = wred_sum4(ex);
        float4 r;                                // first chunk: exp(-inf)=0
        r.x = __expf(m4.x - mn.x); r.y = __expf(m4.y - mn.y);
        r.z = __expf(m4.z - mn.z); r.w = __expf(m4.w - mn.w);
        den4.x = den4.x * r.x + ss.x; den4.y = den4.y * r.y + ss.y;
        den4.z = den4.z * r.z + ss.z; den4.w = den4.w * r.w + ss.w;
        acc4.x *= r.x; acc4.y *= r.y; acc4.z *= r.z; acc4.w *= r.w;
        m4 = mn;
        s_w4[wv][lane] = ex;                     // wave-private; no barrier

        for (int e = 0; e < cnt; e += 4) {
#pragma unroll
            for (int k = 0; k < 4; ++k) {
                int srcn = __shfl(my_src, e + k);          // 0 past cnt
                float4 w4 = s_w4[wv][e + k];               // 0-weights past cnt
                ushort4 v = *(const ushort4*)&xVb[(brow + srcn)*256 + lane*4];
                acc4.x += w4.x * bf2f(v.x);
                acc4.y += w4.y * bf2f(v.y);
                acc4.z += w4.z * bf2f(v.z);
                acc4.w += w4.w * bf2f(v.w);
            }
        }
    }

    float4 o4;
    o4.x = acc4.x / (den4.x + 1e-16f) + att_r[lane];
    o4.y = acc4.y / (den4.y + 1e-16f) + att_r[64 + lane];
    o4.z = acc4.z / (den4.z + 1e-16f) + att_r[128 + lane];
    o4.w = acc4.w / (den4.w + 1e-16f) + att_r[192 + lane];

    float s1 = o4.x + o4.y + o4.z + o4.w;
    float s2 = o4.x*o4.x + o4.y*o4.y + o4.z*o4.z + o4.w*o4.w;
#pragma unroll
    for (int o = 32; o >= 1; o >>= 1) { s1 += __shfl_xor(s1, o); s2 += __shfl_xor(s2, o); }
    float mean = s1 * (1.f/256.f);
    float inv = rsqrtf(s2 * (1.f/256.f) - mean*mean + 1e-5f);

    ushort4 st;
    st.x = f2bf((o4.x - mean) * inv * g0[lane]       + b0[lane]);
    st.y = f2bf((o4.y - mean) * inv * g0[64 + lane]  + b0[64 + lane]);
    st.z = f2bf((o4.z - mean) * inv * g0[128 + lane] + b0[128 + lane]);
    st.w = f2bf((o4.w - mean) * inv * g0[192 + lane] + b0[192 + lane]);
    *(ushort4*)&out0b[(brow + n)*256 + lane*4] = st;     // c-major
}

// ---------------------------------------------------------------------------
// MFMA GEMM: out[M=32768, 256] = A_bf16[M,256] @ W_bf16[n][k]^T (+bias, epilogue)
// MODE 0: out_bf16 = acc+bias, stored C-MAJOR (col' = (col&63)*4 + col>>6);
//         out may ALIAS A in-place (block reads only its own 64 rows first).
// MODE 1: out_bf16 = relu(acc+bias), natural layout      (h)
// MODE 2: y = bf2f(res[c-major]) + relu(acc+bias); out_f32 = LayerNorm1(y)
// BM=64, BN=256 (full row -> LN fits in-block), BK=32, 8 K-steps, 4 waves.
template<int MODE>
__global__ __launch_bounds__(256) void k_mgemm(const ushort* __restrict__ A,
                                               const ushort* __restrict__ Bw,
                                               const float* __restrict__ bias,
                                               const ushort* __restrict__ res,
                                               const float* __restrict__ g,
                                               const float* __restrict__ bvec,
                                               void* __restrict__ outp) {
    __shared__ __align__(16) ushort As[64*32];      // [row][k] 4KB
    __shared__ __align__(16) ushort Bs[256*32];     // [n][k] 16KB
    __shared__ float2 red[64][4];                   // MODE2 row partials

    int t = threadIdx.x;
    int w = t >> 6, lane = t & 63;
    int fr = lane & 15, fg = lane >> 4;
    size_t m0 = (size_t)blockIdx.x * 64;

    int srow = t >> 2;
    int schunk = (t & 3) ^ (srow & 3);         // inverse swizzle on source
    const ushort* gA  = A  + (m0 + srow)*256 + schunk*8;
    const ushort* gB0 = Bw + (size_t)srow*256 + schunk*8;

    int chnk = (fg ^ (fr & 3)) * 8;            // swizzled fragment chunk

    f32x4 acc[4][4];
#pragma unroll
    for (int mt = 0; mt < 4; ++mt)
#pragma unroll
        for (int nt = 0; nt < 4; ++nt) acc[mt][nt] = (f32x4){0.f, 0.f, 0.f, 0.f};

    for (int ks = 0; ks < 8; ++ks) {
        int k0 = ks * 32;
        __builtin_amdgcn_global_load_lds(
            (const __attribute__((address_space(1))) void*)(gA + k0),
            (__attribute__((address_space(3))) void*)(&As[t*8]), 16, 0, 0);
#pragma unroll
        for (int rr = 0; rr < 4; ++rr)
            __builtin_amdgcn_global_load_lds(
                (const __attribute__((address_space(1))) void*)(gB0 + rr*16384 + k0),
                (__attribute__((address_space(3))) void*)(&Bs[rr*2048 + t*8]), 16, 0, 0);
        __syncthreads();

        bf16x8 a[4], b[4];
#pragma unroll
        for (int mt = 0; mt < 4; ++mt)
            a[mt] = *(const bf16x8*)&As[(mt*16 + fr)*32 + chnk];
#pragma unroll
        for (int nt = 0; nt < 4; ++nt)
            b[nt] = *(const bf16x8*)&Bs[(w*64 + nt*16 + fr)*32 + chnk];
#pragma unroll
        for (int mt = 0; mt < 4; ++mt)
#pragma unroll
            for (int nt = 0; nt < 4; ++nt)
                acc[mt][nt] = __builtin_amdgcn_mfma_f32_16x16x32_bf16(
                    a[mt], b[nt], acc[mt][nt], 0, 0, 0);
        __syncthreads();
    }

    // epilogue: C layout col = lane&15 (+nt*16+w*64), row = fg*4+j (+mt*16)
    int colb = w*64 + fr;
    float biasv[4];
#pragma unroll
    for (int nt = 0; nt < 4; ++nt) biasv[nt] = bias[colb + nt*16];

    if (MODE < 2) {
        ushort* ob = (ushort*)outp;
#pragma unroll
        for (int mt = 0; mt < 4; ++mt)
#pragma unroll
            for (int j = 0; j < 4; ++j) {
                int row = mt*16 + fg*4 + j;
#pragma unroll
                for (int nt = 0; nt < 4; ++nt) {
                    float v = acc[mt][nt][j] + biasv[nt];
                    if (MODE == 1) v = fmaxf(v, 0.f);
                    int col = (MODE == 0) ? (((fr + nt*16) << 2) | w)   // c-major
                                          : (colb + nt*16);
                    ob[(m0 + row)*256 + col] = f2bf(v);
                }
            }
    } else {
        float gv[4], bvv[4];
#pragma unroll
        for (int nt = 0; nt < 4; ++nt) { gv[nt] = g[colb + nt*16]; bvv[nt] = bvec[colb + nt*16]; }
#pragma unroll
        for (int mt = 0; mt < 4; ++mt)
#pragma unroll
            for (int j = 0; j < 4; ++j) {
                int row = mt*16 + fg*4 + j;
                float p1 = 0.f, p2 = 0.f;
#pragma unroll
                for (int nt = 0; nt < 4; ++nt) {
                    float v = acc[mt][nt][j] + biasv[nt];
                    int pc = ((fr + nt*16) << 2) | w;         // res is c-major
                    float y = bf2f(res[(m0 + row)*256 + pc]) + fmaxf(v, 0.f);
                    acc[mt][nt][j] = y;
                    p1 += y; p2 += y*y;
                }
#pragma unroll
                for (int o = 8; o >= 1; o >>= 1) { p1 += __shfl_xor(p1, o); p2 += __shfl_xor(p2, o); }
                if (fr == 0) red[row][w] = make_float2(p1, p2);
            }
        __syncthreads();
        float* of = (float*)outp;
#pragma unroll
        for (int mt = 0; mt < 4; ++mt)
#pragma unroll
            for (int j = 0; j < 4; ++j) {
                int row = mt*16 + fg*4 + j;
                float2 s0 = red[row][0], sA = red[row][1], sB = red[row][2], sC = red[row][3];
                float s = s0.x + sA.x + sB.x + sC.x;
                float q = s0.y + sA.y + sB.y + sC.y;
                float mean = s * (1.f/256.f);
                float inv = rsqrtf(q * (1.f/256.f) - mean*mean + 1e-5f);
#pragma unroll
                for (int nt = 0; nt < 4; ++nt)
                    of[(m0 + row)*256 + colb + nt*16] =
                        (acc[mt][nt][j] - mean) * inv * gv[nt] + bvv[nt];
            }
    }
}

// ---------------------------------------------------------------------------
extern "C" void kernel_launch(void* const* d_in, const int* in_sizes, int n_in,
                              void* d_out, int out_size, void* d_ws, size_t ws_size,
                              hipStream_t stream) {
    const float* x     = (const float*)d_in[0];
    const int*   ei    = (const int*)  d_in[1];
    const float* W_K   = (const float*)d_in[2];
    const float* b_K   = (const float*)d_in[3];
    const float* W_V   = (const float*)d_in[4];
    const float* b_V   = (const float*)d_in[5];
    const float* att_r = (const float*)d_in[6];
    const float* ln0_g = (const float*)d_in[7];
    const float* ln0_b = (const float*)d_in[8];
    const float* ln1_g = (const float*)d_in[9];
    const float* ln1_b = (const float*)d_in[10];
    const float* W1    = (const float*)d_in[11];
    const float* b1    = (const float*)d_in[12];
    const float* W2    = (const float*)d_in[13];
    const float* b2    = (const float*)d_in[14];
    float* out = (float*)d_out;

    // workspace layout (bytes). Aliasing plan:
    //   bufA: x_bf16 -> (GEMM0 in-place, c-major) xV_bf16 -> (after agg) h_bf16
    //   bufB: out0_bf16 c-major (lives until GEMM2 residual read)
    char* wsb = (char*)d_ws;
    float*  u     = (float*) (wsb);                 // 4KB
    float*  cvec  = (float*) (wsb + 4096);          // 4 floats (pad 4KB)
    float*  alpha = (float*) (wsb + 8192);          // 512KB
    ushort* WVb   = (ushort*)(wsb + 532480);        // 128KB
    ushort* W1b   = WVb + 65536;                    // 128KB (k-permuted)
    ushort* W2b   = W1b + 65536;                    // 128KB
    int*    ints  = (int*)  (W2b + 65536);
    int* counts   = ints;                           // 4096
    int* cursor   = ints + 4096;                    // 4096
    int* offsets  = ints + 8192;                    // 4097 (pad)
    int* bucket   = ints + 12544;                   // 32768
    ushort* bufA  = (ushort*)(wsb + 1114112);       // 16MB
    ushort* bufB  = bufA + 8388608;                 // 16MB
    size_t need   = 1114112 + 2ull*16777216;        // ~33.1 MB (< proven 35.1)

    if (ws_size < need) return;   // clean fail (visible absmax), no OOB

    hipMemsetAsync(counts, 0, 8192 * sizeof(int), stream);   // counts + cursor

    k_prep_u <<<4, 256, 0, stream>>>(W_K, b_K, att_r, u, cvec);
    k_cvtW   <<<dim3(64, 3), 256, 0, stream>>>(W_V, W1, W2, WVb, W1b, W2b);
    k_alpha  <<<ROWS_/4, 256, 0, stream>>>(x, u, cvec, alpha, bufA);
    k_mgemm<0><<<ROWS_/64, 256, 0, stream>>>(bufA, WVb, b_V, nullptr, nullptr, nullptr, bufA);
    k_hist   <<<E_/256, 256, 0, stream>>>(ei, counts);
    k_scan   <<<1, 256, 0, stream>>>(counts, offsets);
    k_fill   <<<E_/256, 256, 0, stream>>>(ei, offsets, cursor, bucket);
    k_agg_ln0<<<ROWS_/4, 256, 0, stream>>>(alpha, bufA, offsets, bucket,
                                           att_r, ln0_g, ln0_b, bufB);
    k_mgemm<1><<<ROWS_/64, 256, 0, stream>>>(bufB, W1b, b1, nullptr, nullptr, nullptr, bufA);
    k_mgemm<2><<<ROWS_/64, 256, 0, stream>>>(bufA, W2b, b2, bufB, ln1_g, ln1_b, out);
}

// Round 9
// 209.033 us; speedup vs baseline: 1.8117x; 1.0235x over previous
//
#include <hip/hip_runtime.h>
#include <hip/hip_bf16.h>
#include <cstdint>
#include <cstddef>

// Problem constants (fixed by the reference)
#define B_   8
#define N_   4096
#define E_   32768
#define ROWS_ 32768          // B_*N_
#define NEGSLOPE_ 0.2f
#define NEG_INF_ (-3.402823e38f)

typedef __attribute__((ext_vector_type(8))) __bf16 bf16x8;
typedef __attribute__((ext_vector_type(4))) float  f32x4;

__device__ __forceinline__ float lrelu(float v) { return v >= 0.f ? v : NEGSLOPE_ * v; }

__device__ __forceinline__ float bf2f(ushort u) {
    union { uint32_t i; float f; } c; c.i = ((uint32_t)u) << 16; return c.f;
}
__device__ __forceinline__ ushort f2bf(float f) {
    __hip_bfloat16 h = __float2bfloat16(f);          // RNE
    return *reinterpret_cast<ushort*>(&h);
}

__device__ __forceinline__ float4 wred_max4(float4 v) {
#pragma unroll
    for (int o = 32; o >= 1; o >>= 1) {
        v.x = fmaxf(v.x, __shfl_xor(v.x, o));
        v.y = fmaxf(v.y, __shfl_xor(v.y, o));
        v.z = fmaxf(v.z, __shfl_xor(v.z, o));
        v.w = fmaxf(v.w, __shfl_xor(v.w, o));
    }
    return v;
}
__device__ __forceinline__ float4 wred_sum4(float4 v) {
#pragma unroll
    for (int o = 32; o >= 1; o >>= 1) {
        v.x += __shfl_xor(v.x, o);
        v.y += __shfl_xor(v.y, o);
        v.z += __shfl_xor(v.z, o);
        v.w += __shfl_xor(v.w, o);
    }
    return v;
}

// ---------------------------------------------------------------------------
// K0a: u_h[d] = sum_c W_K[h*64+c, d] * att_r[h,c];  c_h = sum_c b_K*att_r
__global__ void k_prep_u(const float* __restrict__ W_K, const float* __restrict__ b_K,
                         const float* __restrict__ att_r,
                         float* __restrict__ u, float* __restrict__ cvec) {
    int h = blockIdx.x;
    int d = threadIdx.x;
    float s = 0.f;
#pragma unroll 8
    for (int c = 0; c < 64; ++c)
        s += W_K[(size_t)(h*64 + c)*256 + d] * att_r[h*64 + c];
    u[h*256 + d] = s;
    if (d == 0) {
        float cs = 0.f;
        for (int c = 0; c < 64; ++c) cs += b_K[h*64 + c] * att_r[h*64 + c];
        cvec[h] = cs;
    }
}

// ---------------------------------------------------------------------------
// K0b: convert the three 256x256 weight matrices to bf16, [n][k] layout.
// W1 additionally gets the k-permutation  k' = (k&63)*4 + (k>>6)  so that it
// matches out0's c-major storage (GEMM is invariant under a shared k-perm).
__global__ void k_cvtW(const float* __restrict__ W_V, const float* __restrict__ W1,
                       const float* __restrict__ W2,
                       ushort* __restrict__ WVb, ushort* __restrict__ W1b,
                       ushort* __restrict__ W2b) {
    int i = blockIdx.x * 1024 + threadIdx.x * 4;
    if (blockIdx.y == 1) {           // W1: permuted read, coalesced write
        int n = i >> 8, c = (i & 255) >> 2;   // output k' = c*4 + h, h=0..3
        const float* s = W1 + (size_t)n*256 + c;
        ushort4 o;
        o.x = f2bf(s[0]);   // h=0 -> orig k = 0*64 + c
        o.y = f2bf(s[64]);
        o.z = f2bf(s[128]);
        o.w = f2bf(s[192]);
        *(ushort4*)&W1b[i] = o;
    } else {
        const float* s = (blockIdx.y == 0) ? W_V : W2;
        ushort* d      = (blockIdx.y == 0) ? WVb : W2b;
        float4 v = *(const float4*)&s[i];
        ushort4 o; o.x = f2bf(v.x); o.y = f2bf(v.y); o.z = f2bf(v.z); o.w = f2bf(v.w);
        *(ushort4*)&d[i] = o;
    }
}

// ---------------------------------------------------------------------------
// K1: alpha[b,n,h] = lrelu(dot(x[row], u_h) + c_h); also emits x in bf16.
// one wave per row; block = 4 waves; grid = ROWS_/4
__global__ void k_alpha(const float* __restrict__ x, const float* __restrict__ u,
                        const float* __restrict__ cvec, float* __restrict__ alpha,
                        ushort* __restrict__ xb) {
    int wave = threadIdx.x >> 6, lane = threadIdx.x & 63;
    size_t row = (size_t)blockIdx.x * 4 + wave;
    const float4* x4 = (const float4*)(x + row*256);
    float4 xv = x4[lane];
    ushort4 xw; xw.x = f2bf(xv.x); xw.y = f2bf(xv.y); xw.z = f2bf(xv.z); xw.w = f2bf(xv.w);
    *(ushort4*)&xb[row*256 + lane*4] = xw;

    const float4* u4 = (const float4*)u;
    float res[4];
#pragma unroll
    for (int h = 0; h < 4; ++h) {
        float4 uv = u4[h*64 + lane];
        float p = xv.x*uv.x + xv.y*uv.y + xv.z*uv.z + xv.w*uv.w;
#pragma unroll
        for (int o = 32; o >= 1; o >>= 1) p += __shfl_xor(p, o);
        res[h] = p;
    }
    if (lane == 0) {
        float4 cv = *(const float4*)cvec;
        float4 o;
        o.x = lrelu(res[0] + cv.x);
        o.y = lrelu(res[1] + cv.y);
        o.z = lrelu(res[2] + cv.z);
        o.w = lrelu(res[3] + cv.w);
        *(float4*)(alpha + row*4) = o;
    }
}

// ---------------------------------------------------------------------------
// CSR build: histogram / scan / fill
__global__ void k_hist(const int* __restrict__ ei, int* __restrict__ counts) {
    int e = blockIdx.x * 256 + threadIdx.x;
    if (e < E_) atomicAdd(&counts[ei[E_ + e]], 1);
}

__global__ void k_scan(const int* __restrict__ counts, int* __restrict__ offsets) {
    __shared__ int tot[256];
    int t = threadIdx.x;
    int local[16];
    int s = 0;
#pragma unroll
    for (int i = 0; i < 16; ++i) { local[i] = s; s += counts[t*16 + i]; }
    tot[t] = s;
    __syncthreads();
    for (int d = 1; d < 256; d <<= 1) {
        int v = (t >= d) ? tot[t - d] : 0;
        __syncthreads();
        tot[t] += v;
        __syncthreads();
    }
    int base = (t == 0) ? 0 : tot[t - 1];
#pragma unroll
    for (int i = 0; i < 16; ++i) offsets[t*16 + i] = base + local[i];
    if (t == 255) offsets[4096] = tot[255];
}

__global__ void k_fill(const int* __restrict__ ei, const int* __restrict__ offsets,
                       int* __restrict__ cursor, int* __restrict__ bucket_src) {
    int e = blockIdx.x * 256 + threadIdx.x;
    if (e >= E_) return;
    int d = ei[E_ + e], srcn = ei[e];
    int pos = atomicAdd(&cursor[d], 1);
    bucket_src[offsets[d] + pos] = srcn;
}

// ---------------------------------------------------------------------------
// K4: ONE WAVE per (n,b) pair. xV is stored c-major [row][c*4+h], so lane
// (=channel c) reads ushort4 = all 4 heads per edge (512 B/wave, coalesced).
// Online softmax per wave; weights broadcast through wave-private LDS; gather
// unrolled x4 (weights past cnt are 0). No __syncthreads. Epilogue: att_r +
// LN0, output c-major bf16.
__global__ __launch_bounds__(256) void k_agg_ln0(
        const float* __restrict__ alpha, const ushort* __restrict__ xVb,
        const int* __restrict__ offsets, const int* __restrict__ bucket_src,
        const float* __restrict__ att_r,
        const float* __restrict__ g0, const float* __restrict__ b0,
        ushort* __restrict__ out0b) {
    __shared__ float4 s_w4[4][64];
    int t = threadIdx.x, wv = t >> 6, lane = t & 63;
    int gp = blockIdx.x * 4 + wv;           // 0..32767
    int n = gp >> 3, b = gp & 7;
    int beg = offsets[n], end = offsets[n + 1];
    size_t brow = (size_t)b * N_;

    float4 m4   = make_float4(NEG_INF_, NEG_INF_, NEG_INF_, NEG_INF_);
    float4 den4 = make_float4(0.f, 0.f, 0.f, 0.f);
    float4 acc4 = make_float4(0.f, 0.f, 0.f, 0.f);

    for (int chunk = beg; chunk < end; chunk += 64) {
        int cnt = min(64, end - chunk);
        int my_src = (lane < cnt) ? bucket_src[chunk + lane] : 0;
        float4 a4 = make_float4(NEG_INF_, NEG_INF_, NEG_INF_, NEG_INF_);
        if (lane < cnt) a4 = *(const float4*)&alpha[(brow + my_src)*4];

        float4 mc = wred_max4(a4);
        float4 mn;
        mn.x = fmaxf(m4.x, mc.x); mn.y = fmaxf(m4.y, mc.y);
        mn.z = fmaxf(m4.z, mc.z); mn.w = fmaxf(m4.w, mc.w);
        float4 ex;                               // lanes >= cnt: exp(-inf)=0
        ex.x = __expf(a4.x - mn.x); ex.y = __expf(a4.y - mn.y);
        ex.z = __expf(a4.z - mn.z); ex.w = __expf(a4.w - mn.w);
        float4 ss = wred_sum4(ex);
        float4 r;                                // first chunk: exp(-inf)=0
        r.x = __expf(m4.x - mn.x); r.y = __expf(m4.y - mn.y);
        r.z = __expf(m4.z - mn.z); r.w = __expf(m4.w - mn.w);
        den4.x = den4.x * r.x + ss.x; den4.y = den4.y * r.y + ss.y;
        den4.z = den4.z * r.z + ss.z; den4.w = den4.w * r.w + ss.w;
        acc4.x *= r.x; acc4.y *= r.y; acc4.z *= r.z; acc4.w *= r.w;
        m4 = mn;
        s_w4[wv][lane] = ex;                     // wave-private; no barrier

        for (int e = 0; e < cnt; e += 4) {
#pragma unroll
            for (int k = 0; k < 4; ++k) {
                int srcn = __shfl(my_src, e + k);          // 0 past cnt
                float4 w4 = s_w4[wv][e + k];               // 0-weights past cnt
                ushort4 v = *(const ushort4*)&xVb[(brow + srcn)*256 + lane*4];
                acc4.x += w4.x * bf2f(v.x);
                acc4.y += w4.y * bf2f(v.y);
                acc4.z += w4.z * bf2f(v.z);
                acc4.w += w4.w * bf2f(v.w);
            }
        }
    }

    float4 o4;
    o4.x = acc4.x / (den4.x + 1e-16f) + att_r[lane];
    o4.y = acc4.y / (den4.y + 1e-16f) + att_r[64 + lane];
    o4.z = acc4.z / (den4.z + 1e-16f) + att_r[128 + lane];
    o4.w = acc4.w / (den4.w + 1e-16f) + att_r[192 + lane];

    float s1 = o4.x + o4.y + o4.z + o4.w;
    float s2 = o4.x*o4.x + o4.y*o4.y + o4.z*o4.z + o4.w*o4.w;
#pragma unroll
    for (int o = 32; o >= 1; o >>= 1) { s1 += __shfl_xor(s1, o); s2 += __shfl_xor(s2, o); }
    float mean = s1 * (1.f/256.f);
    float inv = rsqrtf(s2 * (1.f/256.f) - mean*mean + 1e-5f);

    ushort4 st;
    st.x = f2bf((o4.x - mean) * inv * g0[lane]       + b0[lane]);
    st.y = f2bf((o4.y - mean) * inv * g0[64 + lane]  + b0[64 + lane]);
    st.z = f2bf((o4.z - mean) * inv * g0[128 + lane] + b0[128 + lane]);
    st.w = f2bf((o4.w - mean) * inv * g0[192 + lane] + b0[192 + lane]);
    *(ushort4*)&out0b[(brow + n)*256 + lane*4] = st;     // c-major
}

// ---------------------------------------------------------------------------
// GEMM0: xV[M,256] = x_bf16[M,256] @ W_V^T (+b_V), output stored C-MAJOR
// (col' = c*4 + h). In-place safe (block reads only its own 64 rows first).
// BM=64, BN=256, BK=32, 8 K-steps, 4 waves.
__global__ __launch_bounds__(256) void k_gemm0(const ushort* __restrict__ A,
                                               const ushort* __restrict__ Bw,
                                               const float* __restrict__ bias,
                                               ushort* ob) {
    __shared__ __align__(16) ushort As[64*32];      // 4KB
    __shared__ __align__(16) ushort Bs[256*32];     // 16KB

    int t = threadIdx.x;
    int w = t >> 6, lane = t & 63;
    int fr = lane & 15, fg = lane >> 4;
    size_t m0 = (size_t)blockIdx.x * 64;

    int srow = t >> 2;
    int schunk = (t & 3) ^ (srow & 3);         // inverse swizzle on source
    const ushort* gA  = A  + (m0 + srow)*256 + schunk*8;
    const ushort* gB0 = Bw + (size_t)srow*256 + schunk*8;

    int chnk = (fg ^ (fr & 3)) * 8;            // swizzled fragment chunk

    f32x4 acc[4][4];
#pragma unroll
    for (int mt = 0; mt < 4; ++mt)
#pragma unroll
        for (int nt = 0; nt < 4; ++nt) acc[mt][nt] = (f32x4){0.f, 0.f, 0.f, 0.f};

    for (int ks = 0; ks < 8; ++ks) {
        int k0 = ks * 32;
        __builtin_amdgcn_global_load_lds(
            (const __attribute__((address_space(1))) void*)(gA + k0),
            (__attribute__((address_space(3))) void*)(&As[t*8]), 16, 0, 0);
#pragma unroll
        for (int rr = 0; rr < 4; ++rr)
            __builtin_amdgcn_global_load_lds(
                (const __attribute__((address_space(1))) void*)(gB0 + rr*16384 + k0),
                (__attribute__((address_space(3))) void*)(&Bs[rr*2048 + t*8]), 16, 0, 0);
        __syncthreads();

        bf16x8 a[4], b[4];
#pragma unroll
        for (int mt = 0; mt < 4; ++mt)
            a[mt] = *(const bf16x8*)&As[(mt*16 + fr)*32 + chnk];
#pragma unroll
        for (int nt = 0; nt < 4; ++nt)
            b[nt] = *(const bf16x8*)&Bs[(w*64 + nt*16 + fr)*32 + chnk];
#pragma unroll
        for (int mt = 0; mt < 4; ++mt)
#pragma unroll
            for (int nt = 0; nt < 4; ++nt)
                acc[mt][nt] = __builtin_amdgcn_mfma_f32_16x16x32_bf16(
                    a[mt], b[nt], acc[mt][nt], 0, 0, 0);
        __syncthreads();
    }

    float biasv[4];
#pragma unroll
    for (int nt = 0; nt < 4; ++nt) biasv[nt] = bias[w*64 + fr + nt*16];
#pragma unroll
    for (int mt = 0; mt < 4; ++mt)
#pragma unroll
        for (int j = 0; j < 4; ++j) {
            int row = mt*16 + fg*4 + j;
#pragma unroll
            for (int nt = 0; nt < 4; ++nt) {
                float v = acc[mt][nt][j] + biasv[nt];
                int col = ((fr + nt*16) << 2) | w;   // c-major: c*4+h
                ob[(m0 + row)*256 + col] = f2bf(v);
            }
        }
}

// ---------------------------------------------------------------------------
// K_MLP (fused): per 32-row tile of out0 (c-major):
//   H  = relu(out0 @ W1b^T + b1)          (GEMM1, k'-space; H natural n)
//   Y  = out0 + relu(H @ W2b^T + b2)      (GEMM2; residual from LDS)
//   out = LayerNorm1(Y)                    (f32, natural layout)
// LDS: As_full[8][32][32] (16KB, persistent out0 tile, chunk-swizzled) +
//      Bs[256][32] (16KB, streamed weight chunks) +
//      Hs[32][256] (16KB, row-XOR-swizzled bf16) + red (1KB) = 49KB.
__global__ __launch_bounds__(256) void k_mlp(const ushort* __restrict__ A,
                                             const ushort* __restrict__ W1b,
                                             const float* __restrict__ b1,
                                             const ushort* __restrict__ W2b,
                                             const float* __restrict__ b2,
                                             const float* __restrict__ g,
                                             const float* __restrict__ bvec,
                                             float* __restrict__ out) {
    __shared__ __align__(16) ushort As[8*32*32];    // 16KB persistent A tile
    __shared__ __align__(16) ushort Bs[256*32];     // 16KB weight chunk
    __shared__ __align__(16) ushort Hs[32*256];     // 16KB hidden tile
    __shared__ float2 red[32][4];

    int t = threadIdx.x;
    int w = t >> 6, lane = t & 63;
    int fr = lane & 15, fg = lane >> 4;
    size_t m0 = (size_t)blockIdx.x * 32;

    int srow = t >> 2;                         // A-staging: waves 0-1 only
    int schunk = (t & 3) ^ (srow & 3);
    const ushort* gA  = A   + (m0 + srow)*256 + schunk*8;   // srow<32 for t<128
    const ushort* gW1 = W1b + (size_t)srow*256 + schunk*8;
    const ushort* gW2 = W2b + (size_t)srow*256 + schunk*8;

    int chnk = (fg ^ (fr & 3)) * 8;

    // ---------------- GEMM1: acc1 = A @ W1^T ----------------
    f32x4 acc1[2][4];
#pragma unroll
    for (int mt = 0; mt < 2; ++mt)
#pragma unroll
        for (int nt = 0; nt < 4; ++nt) acc1[mt][nt] = (f32x4){0.f, 0.f, 0.f, 0.f};

    for (int ks = 0; ks < 8; ++ks) {
        int k0 = ks * 32;
        if (t < 128)                               // waves 0-1 (wave-uniform)
            __builtin_amdgcn_global_load_lds(
                (const __attribute__((address_space(1))) void*)(gA + k0),
                (__attribute__((address_space(3))) void*)(&As[ks*1024 + t*8]), 16, 0, 0);
#pragma unroll
        for (int rr = 0; rr < 4; ++rr)
            __builtin_amdgcn_global_load_lds(
                (const __attribute__((address_space(1))) void*)(gW1 + rr*16384 + k0),
                (__attribute__((address_space(3))) void*)(&Bs[rr*2048 + t*8]), 16, 0, 0);
        __syncthreads();

        bf16x8 a[2], b[4];
#pragma unroll
        for (int mt = 0; mt < 2; ++mt)
            a[mt] = *(const bf16x8*)&As[ks*1024 + (mt*16 + fr)*32 + chnk];
#pragma unroll
        for (int nt = 0; nt < 4; ++nt)
            b[nt] = *(const bf16x8*)&Bs[(w*64 + nt*16 + fr)*32 + chnk];
#pragma unroll
        for (int mt = 0; mt < 2; ++mt)
#pragma unroll
            for (int nt = 0; nt < 4; ++nt)
                acc1[mt][nt] = __builtin_amdgcn_mfma_f32_16x16x32_bf16(
                    a[mt], b[nt], acc1[mt][nt], 0, 0, 0);
        __syncthreads();
    }

    // ---------------- epilogue1: Hs = relu(acc1 + b1), swizzled ----------
    int colb = w*64 + fr;
    {
        float b1v[4];
#pragma unroll
        for (int nt = 0; nt < 4; ++nt) b1v[nt] = b1[colb + nt*16];
#pragma unroll
        for (int mt = 0; mt < 2; ++mt)
#pragma unroll
            for (int j = 0; j < 4; ++j) {
                int row = mt*16 + fg*4 + j;
#pragma unroll
                for (int nt = 0; nt < 4; ++nt) {
                    float v = fmaxf(acc1[mt][nt][j] + b1v[nt], 0.f);
                    int byteoff = (row*512 + (colb + nt*16)*2) ^ ((row & 7) << 4);
                    *(ushort*)((char*)Hs + byteoff) = f2bf(v);
                }
            }
    }
    __syncthreads();

    // ---------------- GEMM2: acc2 = Hs @ W2^T ----------------
    f32x4 acc2[2][4];
#pragma unroll
    for (int mt = 0; mt < 2; ++mt)
#pragma unroll
        for (int nt = 0; nt < 4; ++nt) acc2[mt][nt] = (f32x4){0.f, 0.f, 0.f, 0.f};

    for (int ks = 0; ks < 8; ++ks) {
        int k0 = ks * 32;
#pragma unroll
        for (int rr = 0; rr < 4; ++rr)
            __builtin_amdgcn_global_load_lds(
                (const __attribute__((address_space(1))) void*)(gW2 + rr*16384 + k0),
                (__attribute__((address_space(3))) void*)(&Bs[rr*2048 + t*8]), 16, 0, 0);
        __syncthreads();

        bf16x8 a[2], b[4];
#pragma unroll
        for (int mt = 0; mt < 2; ++mt) {
            int row = mt*16 + fr;
            int byteoff = (row*512 + (k0 + fg*8)*2) ^ ((row & 7) << 4);
            a[mt] = *(const bf16x8*)((char*)Hs + byteoff);
        }
#pragma unroll
        for (int nt = 0; nt < 4; ++nt)
            b[nt] = *(const bf16x8*)&Bs[(w*64 + nt*16 + fr)*32 + chnk];
#pragma unroll
        for (int mt = 0; mt < 2; ++mt)
#pragma unroll
            for (int nt = 0; nt < 4; ++nt)
                acc2[mt][nt] = __builtin_amdgcn_mfma_f32_16x16x32_bf16(
                    a[mt], b[nt], acc2[mt][nt], 0, 0, 0);
        __syncthreads();
    }

    // ---------------- epilogue2: residual + LN1 ----------------
    float b2v[4], gv[4], bvv[4];
#pragma unroll
    for (int nt = 0; nt < 4; ++nt) {
        b2v[nt] = b2[colb + nt*16];
        gv[nt]  = g[colb + nt*16];
        bvv[nt] = bvec[colb + nt*16];
    }
#pragma unroll
    for (int mt = 0; mt < 2; ++mt)
#pragma unroll
        for (int j = 0; j < 4; ++j) {
            int row = mt*16 + fg*4 + j;
            float p1 = 0.f, p2 = 0.f;
#pragma unroll
            for (int nt = 0; nt < 4; ++nt) {
                float v = fmaxf(acc2[mt][nt][j] + b2v[nt], 0.f);
                // residual: out0 natural col n=colb+nt*16 -> c-major k'=c*4+h
                int kp  = ((nt*16 + fr) << 2) | w;
                int ks2 = kp >> 5, off = kp & 31;
                int idx = ks2*1024 + row*32 + ((off >> 3) ^ (row & 3))*8 + (off & 7);
                float y = bf2f(As[idx]) + v;
                acc2[mt][nt][j] = y;
                p1 += y; p2 += y*y;
            }
#pragma unroll
            for (int o = 8; o >= 1; o >>= 1) { p1 += __shfl_xor(p1, o); p2 += __shfl_xor(p2, o); }
            if (fr == 0) red[row][w] = make_float2(p1, p2);
        }
    __syncthreads();
#pragma unroll
    for (int mt = 0; mt < 2; ++mt)
#pragma unroll
        for (int j = 0; j < 4; ++j) {
            int row = mt*16 + fg*4 + j;
            float2 s0 = red[row][0], sA = red[row][1], sB = red[row][2], sC = red[row][3];
            float s = s0.x + sA.x + sB.x + sC.x;
            float q = s0.y + sA.y + sB.y + sC.y;
            float mean = s * (1.f/256.f);
            float inv = rsqrtf(q * (1.f/256.f) - mean*mean + 1e-5f);
#pragma unroll
            for (int nt = 0; nt < 4; ++nt)
                out[(m0 + row)*256 + colb + nt*16] =
                    (acc2[mt][nt][j] - mean) * inv * gv[nt] + bvv[nt];
        }
}

// ---------------------------------------------------------------------------
extern "C" void kernel_launch(void* const* d_in, const int* in_sizes, int n_in,
                              void* d_out, int out_size, void* d_ws, size_t ws_size,
                              hipStream_t stream) {
    const float* x     = (const float*)d_in[0];
    const int*   ei    = (const int*)  d_in[1];
    const float* W_K   = (const float*)d_in[2];
    const float* b_K   = (const float*)d_in[3];
    const float* W_V   = (const float*)d_in[4];
    const float* b_V   = (const float*)d_in[5];
    const float* att_r = (const float*)d_in[6];
    const float* ln0_g = (const float*)d_in[7];
    const float* ln0_b = (const float*)d_in[8];
    const float* ln1_g = (const float*)d_in[9];
    const float* ln1_b = (const float*)d_in[10];
    const float* W1    = (const float*)d_in[11];
    const float* b1    = (const float*)d_in[12];
    const float* W2    = (const float*)d_in[13];
    const float* b2    = (const float*)d_in[14];
    float* out = (float*)d_out;

    // workspace layout (bytes). Aliasing plan:
    //   bufA: x_bf16 -> (GEMM0 in-place, c-major) xV_bf16
    //   bufB: out0_bf16 c-major (read by k_mlp for GEMM1 + residual)
    char* wsb = (char*)d_ws;
    float*  u     = (float*) (wsb);                 // 4KB
    float*  cvec  = (float*) (wsb + 4096);          // 4 floats (pad 4KB)
    float*  alpha = (float*) (wsb + 8192);          // 512KB
    ushort* WVb   = (ushort*)(wsb + 532480);        // 128KB
    ushort* W1b   = WVb + 65536;                    // 128KB (k-permuted)
    ushort* W2b   = W1b + 65536;                    // 128KB
    int*    ints  = (int*)  (W2b + 65536);
    int* counts   = ints;                           // 4096
    int* cursor   = ints + 4096;                    // 4096
    int* offsets  = ints + 8192;                    // 4097 (pad)
    int* bucket   = ints + 12544;                   // 32768
    ushort* bufA  = (ushort*)(wsb + 1114112);       // 16MB
    ushort* bufB  = bufA + 8388608;                 // 16MB
    size_t need   = 1114112 + 2ull*16777216;        // ~33.1 MB (< proven 35.1)

    if (ws_size < need) return;   // clean fail (visible absmax), no OOB

    hipMemsetAsync(counts, 0, 8192 * sizeof(int), stream);   // counts + cursor

    k_prep_u <<<4, 256, 0, stream>>>(W_K, b_K, att_r, u, cvec);
    k_cvtW   <<<dim3(64, 3), 256, 0, stream>>>(W_V, W1, W2, WVb, W1b, W2b);
    k_alpha  <<<ROWS_/4, 256, 0, stream>>>(x, u, cvec, alpha, bufA);
    k_gemm0  <<<ROWS_/64, 256, 0, stream>>>(bufA, WVb, b_V, bufA);
    k_hist   <<<E_/256, 256, 0, stream>>>(ei, counts);
    k_scan   <<<1, 256, 0, stream>>>(counts, offsets);
    k_fill   <<<E_/256, 256, 0, stream>>>(ei, offsets, cursor, bucket);
    k_agg_ln0<<<ROWS_/4, 256, 0, stream>>>(alpha, bufA, offsets, bucket,
                                           att_r, ln0_g, ln0_b, bufB);
    k_mlp    <<<ROWS_/32, 256, 0, stream>>>(bufB, W1b, b1, W2b, b2,
                                            ln1_g, ln1_b, out);
}

// Round 10
// 204.397 us; speedup vs baseline: 1.8528x; 1.0227x over previous
//
#include <hip/hip_runtime.h>
#include <hip/hip_bf16.h>
#include <cstdint>
#include <cstddef>

// Problem constants (fixed by the reference)
#define B_   8
#define N_   4096
#define E_   32768
#define ROWS_ 32768          // B_*N_
#define NEGSLOPE_ 0.2f
#define NEG_INF_ (-3.402823e38f)

typedef __attribute__((ext_vector_type(8))) __bf16 bf16x8;
typedef __attribute__((ext_vector_type(4))) float  f32x4;

__device__ __forceinline__ float lrelu(float v) { return v >= 0.f ? v : NEGSLOPE_ * v; }

__device__ __forceinline__ float bf2f(ushort u) {
    union { uint32_t i; float f; } c; c.i = ((uint32_t)u) << 16; return c.f;
}
__device__ __forceinline__ ushort f2bf(float f) {
    __hip_bfloat16 h = __float2bfloat16(f);          // RNE
    return *reinterpret_cast<ushort*>(&h);
}

__device__ __forceinline__ float4 wred_max4(float4 v) {
#pragma unroll
    for (int o = 32; o >= 1; o >>= 1) {
        v.x = fmaxf(v.x, __shfl_xor(v.x, o));
        v.y = fmaxf(v.y, __shfl_xor(v.y, o));
        v.z = fmaxf(v.z, __shfl_xor(v.z, o));
        v.w = fmaxf(v.w, __shfl_xor(v.w, o));
    }
    return v;
}
__device__ __forceinline__ float4 wred_sum4(float4 v) {
#pragma unroll
    for (int o = 32; o >= 1; o >>= 1) {
        v.x += __shfl_xor(v.x, o);
        v.y += __shfl_xor(v.y, o);
        v.z += __shfl_xor(v.z, o);
        v.w += __shfl_xor(v.w, o);
    }
    return v;
}

#define GLDS(gp, lp) __builtin_amdgcn_global_load_lds( \
    (const __attribute__((address_space(1))) void*)(gp), \
    (__attribute__((address_space(3))) void*)(lp), 16, 0, 0)

// ---------------------------------------------------------------------------
// K_SETUP (fused): blocks [0,192) cvtW | [192,196) prep_u | [196,324) hist
__global__ __launch_bounds__(256) void k_setup(
        const float* __restrict__ W_K, const float* __restrict__ b_K,
        const float* __restrict__ att_r, float* __restrict__ u,
        float* __restrict__ cvec,
        const float* __restrict__ W_V, const float* __restrict__ W1,
        const float* __restrict__ W2,
        ushort* __restrict__ WVb, ushort* __restrict__ W1b,
        ushort* __restrict__ W2b,
        const int* __restrict__ ei, int* __restrict__ counts) {
    int bid = blockIdx.x, t = threadIdx.x;
    if (bid < 192) {                       // --- cvtW (64 x 3) ---
        int bx = bid & 63, by = bid >> 6;
        int i = bx * 1024 + t * 4;
        if (by == 1) {                     // W1: k-permuted (k' = c*4 + h)
            int n = i >> 8, c = (i & 255) >> 2;
            const float* s = W1 + (size_t)n*256 + c;
            ushort4 o;
            o.x = f2bf(s[0]); o.y = f2bf(s[64]); o.z = f2bf(s[128]); o.w = f2bf(s[192]);
            *(ushort4*)&W1b[i] = o;
        } else {
            const float* s = (by == 0) ? W_V : W2;
            ushort* d      = (by == 0) ? WVb : W2b;
            float4 v = *(const float4*)&s[i];
            ushort4 o; o.x = f2bf(v.x); o.y = f2bf(v.y); o.z = f2bf(v.z); o.w = f2bf(v.w);
            *(ushort4*)&d[i] = o;
        }
    } else if (bid < 196) {                // --- prep_u ---
        int h = bid - 192, d = t;
        float s = 0.f;
#pragma unroll 8
        for (int c = 0; c < 64; ++c)
            s += W_K[(size_t)(h*64 + c)*256 + d] * att_r[h*64 + c];
        u[h*256 + d] = s;
        if (d == 0) {
            float cs = 0.f;
            for (int c = 0; c < 64; ++c) cs += b_K[h*64 + c] * att_r[h*64 + c];
            cvec[h] = cs;
        }
    } else {                               // --- hist ---
        int e = (bid - 196) * 256 + t;
        if (e < E_) atomicAdd(&counts[ei[E_ + e]], 1);
    }
}

// ---------------------------------------------------------------------------
// K1: alpha[b,n,h] = lrelu(dot(x[row], u_h) + c_h); also emits x in bf16.
__global__ void k_alpha(const float* __restrict__ x, const float* __restrict__ u,
                        const float* __restrict__ cvec, float* __restrict__ alpha,
                        ushort* __restrict__ xb) {
    int wave = threadIdx.x >> 6, lane = threadIdx.x & 63;
    size_t row = (size_t)blockIdx.x * 4 + wave;
    const float4* x4 = (const float4*)(x + row*256);
    float4 xv = x4[lane];
    ushort4 xw; xw.x = f2bf(xv.x); xw.y = f2bf(xv.y); xw.z = f2bf(xv.z); xw.w = f2bf(xv.w);
    *(ushort4*)&xb[row*256 + lane*4] = xw;

    const float4* u4 = (const float4*)u;
    float res[4];
#pragma unroll
    for (int h = 0; h < 4; ++h) {
        float4 uv = u4[h*64 + lane];
        float p = xv.x*uv.x + xv.y*uv.y + xv.z*uv.z + xv.w*uv.w;
#pragma unroll
        for (int o = 32; o >= 1; o >>= 1) p += __shfl_xor(p, o);
        res[h] = p;
    }
    if (lane == 0) {
        float4 cv = *(const float4*)cvec;
        float4 o;
        o.x = lrelu(res[0] + cv.x);
        o.y = lrelu(res[1] + cv.y);
        o.z = lrelu(res[2] + cv.z);
        o.w = lrelu(res[3] + cv.w);
        *(float4*)(alpha + row*4) = o;
    }
}

// ---------------------------------------------------------------------------
__global__ void k_scan(const int* __restrict__ counts, int* __restrict__ offsets) {
    __shared__ int tot[256];
    int t = threadIdx.x;
    int local[16];
    int s = 0;
#pragma unroll
    for (int i = 0; i < 16; ++i) { local[i] = s; s += counts[t*16 + i]; }
    tot[t] = s;
    __syncthreads();
    for (int d = 1; d < 256; d <<= 1) {
        int v = (t >= d) ? tot[t - d] : 0;
        __syncthreads();
        tot[t] += v;
        __syncthreads();
    }
    int base = (t == 0) ? 0 : tot[t - 1];
#pragma unroll
    for (int i = 0; i < 16; ++i) offsets[t*16 + i] = base + local[i];
    if (t == 255) offsets[4096] = tot[255];
}

// ---------------------------------------------------------------------------
// K_G0F (fused): blocks [0,512) = GEMM0 (xV, c-major, in-place, 2-phase
// pipelined, LDS-transposed coalesced epilogue) | [512,640) = CSR fill.
__global__ __launch_bounds__(256) void k_g0f(const ushort* __restrict__ A,
                                             const ushort* __restrict__ Bw,
                                             const float* __restrict__ bias,
                                             ushort* ob,
                                             const int* __restrict__ ei,
                                             const int* __restrict__ offsets,
                                             int* __restrict__ cursor,
                                             int* __restrict__ bucket) {
    __shared__ __align__(16) ushort sA[2][2048];    // 2 x 4KB
    __shared__ __align__(16) ushort sB[2][8192];    // 2 x 16KB
    int t = threadIdx.x;

    if (blockIdx.x >= 512) {               // --- CSR fill ---
        int e = (blockIdx.x - 512) * 256 + t;
        if (e < E_) {
            int d = ei[E_ + e], srcn = ei[e];
            int pos = atomicAdd(&cursor[d], 1);
            bucket[offsets[d] + pos] = srcn;
        }
        return;
    }

    int w = t >> 6, lane = t & 63;
    int fr = lane & 15, fg = lane >> 4;
    size_t m0 = (size_t)blockIdx.x * 64;

    int srow = t >> 2;
    int schunk = (t & 3) ^ (srow & 3);
    const ushort* gA  = A  + (m0 + srow)*256 + schunk*8;
    const ushort* gB0 = Bw + (size_t)srow*256 + schunk*8;
    int chnk = (fg ^ (fr & 3)) * 8;

    f32x4 acc[4][4];
#pragma unroll
    for (int mt = 0; mt < 4; ++mt)
#pragma unroll
        for (int nt = 0; nt < 4; ++nt) acc[mt][nt] = (f32x4){0.f, 0.f, 0.f, 0.f};

    auto STAGE = [&](int buf, int ks) {
        int k0 = ks * 32;
        GLDS(gA + k0, &sA[buf][t*8]);
#pragma unroll
        for (int rr = 0; rr < 4; ++rr)
            GLDS(gB0 + rr*16384 + k0, &sB[buf][rr*2048 + t*8]);
    };

    STAGE(0, 0);
    __syncthreads();
    for (int ks = 0; ks < 8; ++ks) {
        int cur = ks & 1;
        if (ks < 7) STAGE(cur ^ 1, ks + 1);        // overlap with compute
        bf16x8 a[4], b[4];
#pragma unroll
        for (int mt = 0; mt < 4; ++mt)
            a[mt] = *(const bf16x8*)&sA[cur][(mt*16 + fr)*32 + chnk];
#pragma unroll
        for (int nt = 0; nt < 4; ++nt)
            b[nt] = *(const bf16x8*)&sB[cur][(w*64 + nt*16 + fr)*32 + chnk];
#pragma unroll
        for (int mt = 0; mt < 4; ++mt)
#pragma unroll
            for (int nt = 0; nt < 4; ++nt)
                acc[mt][nt] = __builtin_amdgcn_mfma_f32_16x16x32_bf16(
                    a[mt], b[nt], acc[mt][nt], 0, 0, 0);
        __syncthreads();                            // drains next-stage too
    }

    // epilogue: c-major tile in LDS (reuse sB, 32KB), then coalesced copy-out
    ushort* tile = &sB[0][0];                       // [64][256] ushort
    float biasv[4];
#pragma unroll
    for (int nt = 0; nt < 4; ++nt) biasv[nt] = bias[w*64 + fr + nt*16];
#pragma unroll
    for (int mt = 0; mt < 4; ++mt)
#pragma unroll
        for (int j = 0; j < 4; ++j) {
            int row = mt*16 + fg*4 + j;
#pragma unroll
            for (int nt = 0; nt < 4; ++nt) {
                float v = acc[mt][nt][j] + biasv[nt];
                tile[row*256 + (((fr + nt*16) << 2) | w)] = f2bf(v);
            }
        }
    __syncthreads();
    const int4* ts = (const int4*)tile;
    int4* td = (int4*)(ob + m0*256);                // 32KB contiguous
#pragma unroll
    for (int i = 0; i < 8; ++i) td[i*256 + t] = ts[i*256 + t];
}

// ---------------------------------------------------------------------------
// K4: ONE WAVE per (n,b) pair; c-major xV; online softmax; gather unroll x8.
__global__ __launch_bounds__(256) void k_agg_ln0(
        const float* __restrict__ alpha, const ushort* __restrict__ xVb,
        const int* __restrict__ offsets, const int* __restrict__ bucket_src,
        const float* __restrict__ att_r,
        const float* __restrict__ g0, const float* __restrict__ b0,
        ushort* __restrict__ out0b) {
    __shared__ float4 s_w4[4][64];
    int t = threadIdx.x, wv = t >> 6, lane = t & 63;
    int gp = blockIdx.x * 4 + wv;
    int n = gp >> 3, b = gp & 7;
    int beg = offsets[n], end = offsets[n + 1];
    size_t brow = (size_t)b * N_;

    float4 m4   = make_float4(NEG_INF_, NEG_INF_, NEG_INF_, NEG_INF_);
    float4 den4 = make_float4(0.f, 0.f, 0.f, 0.f);
    float4 acc4 = make_float4(0.f, 0.f, 0.f, 0.f);

    for (int chunk = beg; chunk < end; chunk += 64) {
        int cnt = min(64, end - chunk);
        int my_src = (lane < cnt) ? bucket_src[chunk + lane] : 0;
        float4 a4 = make_float4(NEG_INF_, NEG_INF_, NEG_INF_, NEG_INF_);
        if (lane < cnt) a4 = *(const float4*)&alpha[(brow + my_src)*4];

        float4 mc = wred_max4(a4);
        float4 mn;
        mn.x = fmaxf(m4.x, mc.x); mn.y = fmaxf(m4.y, mc.y);
        mn.z = fmaxf(m4.z, mc.z); mn.w = fmaxf(m4.w, mc.w);
        float4 ex;
        ex.x = __expf(a4.x - mn.x); ex.y = __expf(a4.y - mn.y);
        ex.z = __expf(a4.z - mn.z); ex.w = __expf(a4.w - mn.w);
        float4 ss = wred_sum4(ex);
        float4 r;
        r.x = __expf(m4.x - mn.x); r.y = __expf(m4.y - mn.y);
        r.z = __expf(m4.z - mn.z); r.w = __expf(m4.w - mn.w);
        den4.x = den4.x * r.x + ss.x; den4.y = den4.y * r.y + ss.y;
        den4.z = den4.z * r.z + ss.z; den4.w = den4.w * r.w + ss.w;
        acc4.x *= r.x; acc4.y *= r.y; acc4.z *= r.z; acc4.w *= r.w;
        m4 = mn;
        s_w4[wv][lane] = ex;                 // wave-private; no barrier

        for (int e = 0; e < cnt; e += 8) {
#pragma unroll
            for (int k = 0; k < 8; ++k) {    // 8 loads in flight
                int srcn = __shfl(my_src, e + k);
                float4 w4 = s_w4[wv][e + k];
                ushort4 v = *(const ushort4*)&xVb[(brow + srcn)*256 + lane*4];
                acc4.x += w4.x * bf2f(v.x);
                acc4.y += w4.y * bf2f(v.y);
                acc4.z += w4.z * bf2f(v.z);
                acc4.w += w4.w * bf2f(v.w);
            }
        }
    }

    float4 o4;
    o4.x = acc4.x / (den4.x + 1e-16f) + att_r[lane];
    o4.y = acc4.y / (den4.y + 1e-16f) + att_r[64 + lane];
    o4.z = acc4.z / (den4.z + 1e-16f) + att_r[128 + lane];
    o4.w = acc4.w / (den4.w + 1e-16f) + att_r[192 + lane];

    float s1 = o4.x + o4.y + o4.z + o4.w;
    float s2 = o4.x*o4.x + o4.y*o4.y + o4.z*o4.z + o4.w*o4.w;
#pragma unroll
    for (int o = 32; o >= 1; o >>= 1) { s1 += __shfl_xor(s1, o); s2 += __shfl_xor(s2, o); }
    float mean = s1 * (1.f/256.f);
    float inv = rsqrtf(s2 * (1.f/256.f) - mean*mean + 1e-5f);

    ushort4 st;
    st.x = f2bf((o4.x - mean) * inv * g0[lane]       + b0[lane]);
    st.y = f2bf((o4.y - mean) * inv * g0[64 + lane]  + b0[64 + lane]);
    st.z = f2bf((o4.z - mean) * inv * g0[128 + lane] + b0[128 + lane]);
    st.w = f2bf((o4.w - mean) * inv * g0[192 + lane] + b0[192 + lane]);
    *(ushort4*)&out0b[(brow + n)*256 + lane*4] = st;     // c-major
}

// ---------------------------------------------------------------------------
// K_MLP (fused, pipelined): full A-tile preloaded (16KB); W chunks
// double-buffered (2x16KB); Hs 16KB (row-XOR swizzle); red aliased on Hs;
// output staged in LDS (aliased on Bs) for coalesced f32 copy-out. 64KB LDS.
__global__ __launch_bounds__(256) void k_mlp(const ushort* __restrict__ Ain,
                                             const ushort* __restrict__ W1b,
                                             const float* __restrict__ b1,
                                             const ushort* __restrict__ W2b,
                                             const float* __restrict__ b2,
                                             const float* __restrict__ g,
                                             const float* __restrict__ bvec,
                                             float* __restrict__ out) {
    __shared__ __align__(16) ushort As[8192];       // 16KB persistent A tile
    __shared__ __align__(16) ushort Bs[2][8192];    // 32KB weight dbuf
    __shared__ __align__(16) ushort Hs[8192];       // 16KB hidden tile

    int t = threadIdx.x;
    int w = t >> 6, lane = t & 63;
    int fr = lane & 15, fg = lane >> 4;
    size_t m0 = (size_t)blockIdx.x * 32;

    int srow = t >> 2;
    int schunk = (t & 3) ^ (srow & 3);
    const ushort* gW1 = W1b + (size_t)srow*256 + schunk*8;
    const ushort* gW2 = W2b + (size_t)srow*256 + schunk*8;
    int chnk = (fg ^ (fr & 3)) * 8;

    auto stageW = [&](int buf, const ushort* gW, int ks) {
        int k0 = ks * 32;
#pragma unroll
        for (int rr = 0; rr < 4; ++rr)
            GLDS(gW + rr*16384 + k0, &Bs[buf][rr*2048 + t*8]);
    };

    // prologue: full A preload (4 passes) + W1 chunk 0
    {
        int row = (t >> 2) & 31, cs = t & 3, sc = cs ^ (row & 3);
#pragma unroll
        for (int p = 0; p < 4; ++p) {
            int ks = p*2 + (t >> 7);
            GLDS(Ain + (m0 + row)*256 + ks*32 + sc*8, &As[p*2048 + t*8]);
        }
    }
    stageW(0, gW1, 0);
    __syncthreads();

    // ---------------- GEMM1 ----------------
    f32x4 acc1[2][4];
#pragma unroll
    for (int mt = 0; mt < 2; ++mt)
#pragma unroll
        for (int nt = 0; nt < 4; ++nt) acc1[mt][nt] = (f32x4){0.f, 0.f, 0.f, 0.f};

    for (int ks = 0; ks < 8; ++ks) {
        int cur = ks & 1;
        if (ks < 7) stageW(cur ^ 1, gW1, ks + 1);
        bf16x8 a[2], b[4];
#pragma unroll
        for (int mt = 0; mt < 2; ++mt)
            a[mt] = *(const bf16x8*)&As[ks*1024 + (mt*16 + fr)*32 + chnk];
#pragma unroll
        for (int nt = 0; nt < 4; ++nt)
            b[nt] = *(const bf16x8*)&Bs[cur][(w*64 + nt*16 + fr)*32 + chnk];
#pragma unroll
        for (int mt = 0; mt < 2; ++mt)
#pragma unroll
            for (int nt = 0; nt < 4; ++nt)
                acc1[mt][nt] = __builtin_amdgcn_mfma_f32_16x16x32_bf16(
                    a[mt], b[nt], acc1[mt][nt], 0, 0, 0);
        __syncthreads();
    }

    // stage W2 chunk 0 early (Bs[0] free: last read at ks=6, sync'd)
    stageW(0, gW2, 0);

    // epilogue1: Hs = relu(acc1 + b1), row-XOR swizzled
    int colb = w*64 + fr;
    {
        float b1v[4];
#pragma unroll
        for (int nt = 0; nt < 4; ++nt) b1v[nt] = b1[colb + nt*16];
#pragma unroll
        for (int mt = 0; mt < 2; ++mt)
#pragma unroll
            for (int j = 0; j < 4; ++j) {
                int row = mt*16 + fg*4 + j;
#pragma unroll
                for (int nt = 0; nt < 4; ++nt) {
                    float v = fmaxf(acc1[mt][nt][j] + b1v[nt], 0.f);
                    int byteoff = (row*512 + (colb + nt*16)*2) ^ ((row & 7) << 4);
                    *(ushort*)((char*)Hs + byteoff) = f2bf(v);
                }
            }
    }
    __syncthreads();                         // Hs visible + W2 ks0 drained

    // ---------------- GEMM2 ----------------
    f32x4 acc2[2][4];
#pragma unroll
    for (int mt = 0; mt < 2; ++mt)
#pragma unroll
        for (int nt = 0; nt < 4; ++nt) acc2[mt][nt] = (f32x4){0.f, 0.f, 0.f, 0.f};

    for (int ks = 0; ks < 8; ++ks) {
        int cur = ks & 1;
        if (ks < 7) stageW(cur ^ 1, gW2, ks + 1);
        int k0 = ks * 32;
        bf16x8 a[2], b[4];
#pragma unroll
        for (int mt = 0; mt < 2; ++mt) {
            int row = mt*16 + fr;
            int byteoff = (row*512 + (k0 + fg*8)*2) ^ ((row & 7) << 4);
            a[mt] = *(const bf16x8*)((char*)Hs + byteoff);
        }
#pragma unroll
        for (int nt = 0; nt < 4; ++nt)
            b[nt] = *(const bf16x8*)&Bs[cur][(w*64 + nt*16 + fr)*32 + chnk];
#pragma unroll
        for (int mt = 0; mt < 2; ++mt)
#pragma unroll
            for (int nt = 0; nt < 4; ++nt)
                acc2[mt][nt] = __builtin_amdgcn_mfma_f32_16x16x32_bf16(
                    a[mt], b[nt], acc2[mt][nt], 0, 0, 0);
        __syncthreads();
    }

    // epilogue2: residual (from As) + LN1; red aliased on Hs (free now)
    float2 (*red)[4] = (float2(*)[4])Hs;
    float b2v[4], gv[4], bvv[4];
#pragma unroll
    for (int nt = 0; nt < 4; ++nt) {
        b2v[nt] = b2[colb + nt*16];
        gv[nt]  = g[colb + nt*16];
        bvv[nt] = bvec[colb + nt*16];
    }
#pragma unroll
    for (int mt = 0; mt < 2; ++mt)
#pragma unroll
        for (int j = 0; j < 4; ++j) {
            int row = mt*16 + fg*4 + j;
            float p1 = 0.f, p2 = 0.f;
#pragma unroll
            for (int nt = 0; nt < 4; ++nt) {
                float v = fmaxf(acc2[mt][nt][j] + b2v[nt], 0.f);
                int kp  = ((nt*16 + fr) << 2) | w;        // res c-major index
                int ks2 = kp >> 5, off = kp & 31;
                int idx = ks2*1024 + row*32 + ((off >> 3) ^ (row & 3))*8 + (off & 7);
                float y = bf2f(As[idx]) + v;
                acc2[mt][nt][j] = y;
                p1 += y; p2 += y*y;
            }
#pragma unroll
            for (int o = 8; o >= 1; o >>= 1) { p1 += __shfl_xor(p1, o); p2 += __shfl_xor(p2, o); }
            if (fr == 0) red[row][w] = make_float2(p1, p2);
        }
    __syncthreads();

    // LN + stage f32 tile in LDS (alias Bs, 32KB) for coalesced copy-out
    float* tileF = (float*)&Bs[0][0];               // [32][256] f32
#pragma unroll
    for (int mt = 0; mt < 2; ++mt)
#pragma unroll
        for (int j = 0; j < 4; ++j) {
            int row = mt*16 + fg*4 + j;
            float2 s0 = red[row][0], sA2 = red[row][1], sB2 = red[row][2], sC = red[row][3];
            float s = s0.x + sA2.x + sB2.x + sC.x;
            float q = s0.y + sA2.y + sB2.y + sC.y;
            float mean = s * (1.f/256.f);
            float inv = rsqrtf(q * (1.f/256.f) - mean*mean + 1e-5f);
#pragma unroll
            for (int nt = 0; nt < 4; ++nt)
                tileF[row*256 + colb + nt*16] =
                    (acc2[mt][nt][j] - mean) * inv * gv[nt] + bvv[nt];
        }
    __syncthreads();
    const int4* ts = (const int4*)tileF;
    int4* td = (int4*)(out + m0*256);               // 32KB contiguous
#pragma unroll
    for (int i = 0; i < 8; ++i) td[i*256 + t] = ts[i*256 + t];
}

// ---------------------------------------------------------------------------
extern "C" void kernel_launch(void* const* d_in, const int* in_sizes, int n_in,
                              void* d_out, int out_size, void* d_ws, size_t ws_size,
                              hipStream_t stream) {
    const float* x     = (const float*)d_in[0];
    const int*   ei    = (const int*)  d_in[1];
    const float* W_K   = (const float*)d_in[2];
    const float* b_K   = (const float*)d_in[3];
    const float* W_V   = (const float*)d_in[4];
    const float* b_V   = (const float*)d_in[5];
    const float* att_r = (const float*)d_in[6];
    const float* ln0_g = (const float*)d_in[7];
    const float* ln0_b = (const float*)d_in[8];
    const float* ln1_g = (const float*)d_in[9];
    const float* ln1_b = (const float*)d_in[10];
    const float* W1    = (const float*)d_in[11];
    const float* b1    = (const float*)d_in[12];
    const float* W2    = (const float*)d_in[13];
    const float* b2    = (const float*)d_in[14];
    float* out = (float*)d_out;

    // workspace layout (bytes). Aliasing:
    //   bufA: x_bf16 -> (k_g0f in-place, c-major) xV_bf16
    //   bufB: out0_bf16 c-major (k_mlp input + residual)
    char* wsb = (char*)d_ws;
    float*  u     = (float*) (wsb);                 // 4KB
    float*  cvec  = (float*) (wsb + 4096);          // pad 4KB
    float*  alpha = (float*) (wsb + 8192);          // 512KB
    ushort* WVb   = (ushort*)(wsb + 532480);        // 128KB
    ushort* W1b   = WVb + 65536;                    // 128KB (k-permuted)
    ushort* W2b   = W1b + 65536;                    // 128KB
    int*    ints  = (int*)  (W2b + 65536);
    int* counts   = ints;                           // 4096
    int* cursor   = ints + 4096;                    // 4096
    int* offsets  = ints + 8192;                    // 4097 (pad)
    int* bucket   = ints + 12544;                   // 32768
    ushort* bufA  = (ushort*)(wsb + 1114112);       // 16MB
    ushort* bufB  = bufA + 8388608;                 // 16MB
    size_t need   = 1114112 + 2ull*16777216;        // ~33.1 MB

    if (ws_size < need) return;   // clean fail, no OOB

    hipMemsetAsync(counts, 0, 8192 * sizeof(int), stream);   // counts + cursor

    k_setup  <<<324, 256, 0, stream>>>(W_K, b_K, att_r, u, cvec,
                                       W_V, W1, W2, WVb, W1b, W2b, ei, counts);
    k_alpha  <<<ROWS_/4, 256, 0, stream>>>(x, u, cvec, alpha, bufA);
    k_scan   <<<1, 256, 0, stream>>>(counts, offsets);
    k_g0f    <<<640, 256, 0, stream>>>(bufA, WVb, b_V, bufA,
                                       ei, offsets, cursor, bucket);
    k_agg_ln0<<<ROWS_/4, 256, 0, stream>>>(alpha, bufA, offsets, bucket,
                                           att_r, ln0_g, ln0_b, bufB);
    k_mlp    <<<ROWS_/32, 256, 0, stream>>>(bufB, W1b, b1, W2b, b2,
                                            ln1_g, ln1_b, out);
}

// Round 14
// 191.911 us; speedup vs baseline: 1.9733x; 1.0651x over previous
//
#include <hip/hip_runtime.h>
#include <hip/hip_bf16.h>
#include <cstdint>
#include <cstddef>

// Problem constants (fixed by the reference)
#define B_   8
#define N_   4096
#define E_   32768
#define ROWS_ 32768          // B_*N_
#define NEGSLOPE_ 0.2f
#define NEG_INF_ (-3.402823e38f)

typedef __attribute__((ext_vector_type(8))) __bf16 bf16x8;
typedef __attribute__((ext_vector_type(4))) float  f32x4;

__device__ __forceinline__ float lrelu(float v) { return v >= 0.f ? v : NEGSLOPE_ * v; }

__device__ __forceinline__ float bf2f(ushort u) {
    union { uint32_t i; float f; } c; c.i = ((uint32_t)u) << 16; return c.f;
}
__device__ __forceinline__ ushort f2bf(float f) {
    __hip_bfloat16 h = __float2bfloat16(f);          // RNE
    return *reinterpret_cast<ushort*>(&h);
}

#define GLDS(gp, lp) __builtin_amdgcn_global_load_lds( \
    (const __attribute__((address_space(1))) void*)(gp), \
    (__attribute__((address_space(3))) void*)(lp), 16, 0, 0)

// ---------------------------------------------------------------------------
// K_SETUP (fused): blocks [0,192) cvtW | [192,196) prep_u | [196,324) hist
__global__ __launch_bounds__(256) void k_setup(
        const float* __restrict__ W_K, const float* __restrict__ b_K,
        const float* __restrict__ att_r, float* __restrict__ u,
        float* __restrict__ cvec,
        const float* __restrict__ W_V, const float* __restrict__ W1,
        const float* __restrict__ W2,
        ushort* __restrict__ WVb, ushort* __restrict__ W1b,
        ushort* __restrict__ W2b,
        const int* __restrict__ ei, int* __restrict__ counts) {
    int bid = blockIdx.x, t = threadIdx.x;
    if (bid < 192) {                       // --- cvtW (64 x 3) ---
        int bx = bid & 63, by = bid >> 6;
        int i = bx * 1024 + t * 4;
        if (by == 1) {                     // W1: k-permuted (k' = c*4 + h)
            int n = i >> 8, c = (i & 255) >> 2;
            const float* s = W1 + (size_t)n*256 + c;
            ushort4 o;
            o.x = f2bf(s[0]); o.y = f2bf(s[64]); o.z = f2bf(s[128]); o.w = f2bf(s[192]);
            *(ushort4*)&W1b[i] = o;
        } else {
            const float* s = (by == 0) ? W_V : W2;
            ushort* d      = (by == 0) ? WVb : W2b;
            float4 v = *(const float4*)&s[i];
            ushort4 o; o.x = f2bf(v.x); o.y = f2bf(v.y); o.z = f2bf(v.z); o.w = f2bf(v.w);
            *(ushort4*)&d[i] = o;
        }
    } else if (bid < 196) {                // --- prep_u ---
        int h = bid - 192, d = t;
        float s = 0.f;
#pragma unroll 8
        for (int c = 0; c < 64; ++c)
            s += W_K[(size_t)(h*64 + c)*256 + d] * att_r[h*64 + c];
        u[h*256 + d] = s;
        if (d == 0) {
            float cs = 0.f;
            for (int c = 0; c < 64; ++c) cs += b_K[h*64 + c] * att_r[h*64 + c];
            cvec[h] = cs;
        }
    } else {                               // --- hist ---
        int e = (bid - 196) * 256 + t;
        if (e < E_) atomicAdd(&counts[ei[E_ + e]], 1);
    }
}

// ---------------------------------------------------------------------------
// K1: alpha_t[n][b][h] = lrelu(dot(x[row], u_h) + c_h); also emits x in bf16.
__global__ void k_alpha(const float* __restrict__ x, const float* __restrict__ u,
                        const float* __restrict__ cvec, float* __restrict__ alpha_t,
                        ushort* __restrict__ xb) {
    int wave = threadIdx.x >> 6, lane = threadIdx.x & 63;
    size_t row = (size_t)blockIdx.x * 4 + wave;
    const float4* x4 = (const float4*)(x + row*256);
    float4 xv = x4[lane];
    ushort4 xw; xw.x = f2bf(xv.x); xw.y = f2bf(xv.y); xw.z = f2bf(xv.z); xw.w = f2bf(xv.w);
    *(ushort4*)&xb[row*256 + lane*4] = xw;

    const float4* u4 = (const float4*)u;
    float res[4];
#pragma unroll
    for (int h = 0; h < 4; ++h) {
        float4 uv = u4[h*64 + lane];
        float p = xv.x*uv.x + xv.y*uv.y + xv.z*uv.z + xv.w*uv.w;
#pragma unroll
        for (int o = 32; o >= 1; o >>= 1) p += __shfl_xor(p, o);
        res[h] = p;
    }
    if (lane == 0) {
        float4 cv = *(const float4*)cvec;
        float4 o;
        o.x = lrelu(res[0] + cv.x);
        o.y = lrelu(res[1] + cv.y);
        o.z = lrelu(res[2] + cv.z);
        o.w = lrelu(res[3] + cv.w);
        int n = (int)(row & 4095), b = (int)(row >> 12);
        *(float4*)(alpha_t + n*32 + b*4) = o;      // [n][b][h]
    }
}

// ---------------------------------------------------------------------------
__global__ void k_scan(const int* __restrict__ counts, int* __restrict__ offsets) {
    __shared__ int tot[256];
    int t = threadIdx.x;
    int local[16];
    int s = 0;
#pragma unroll
    for (int i = 0; i < 16; ++i) { local[i] = s; s += counts[t*16 + i]; }
    tot[t] = s;
    __syncthreads();
    for (int d = 1; d < 256; d <<= 1) {
        int v = (t >= d) ? tot[t - d] : 0;
        __syncthreads();
        tot[t] += v;
        __syncthreads();
    }
    int base = (t == 0) ? 0 : tot[t - 1];
#pragma unroll
    for (int i = 0; i < 16; ++i) offsets[t*16 + i] = base + local[i];
    if (t == 255) offsets[4096] = tot[255];
}

// ---------------------------------------------------------------------------
// K_G0F (fused): blocks [0,512) = GEMM0 (xV, 2-phase pipelined) writing the
// n-major layout xVt[n][b][c-major 256] into a SEPARATE buffer (not in-place:
// the n-major scatter would alias other blocks' unread inputs) |
// [512,640) = CSR fill.
__global__ __launch_bounds__(256) void k_g0f(const ushort* __restrict__ A,
                                             const ushort* __restrict__ Bw,
                                             const float* __restrict__ bias,
                                             ushort* __restrict__ ob,
                                             const int* __restrict__ ei,
                                             const int* __restrict__ offsets,
                                             int* __restrict__ cursor,
                                             int* __restrict__ bucket) {
    __shared__ __align__(16) ushort sA[2][2048];    // 2 x 4KB
    __shared__ __align__(16) ushort sB[2][8192];    // 2 x 16KB
    int t = threadIdx.x;

    if (blockIdx.x >= 512) {               // --- CSR fill ---
        int e = (blockIdx.x - 512) * 256 + t;
        if (e < E_) {
            int d = ei[E_ + e], srcn = ei[e];
            int pos = atomicAdd(&cursor[d], 1);
            bucket[offsets[d] + pos] = srcn;
        }
        return;
    }

    int w = t >> 6, lane = t & 63;
    int fr = lane & 15, fg = lane >> 4;
    size_t m0 = (size_t)blockIdx.x * 64;

    int srow = t >> 2;
    int schunk = (t & 3) ^ (srow & 3);
    const ushort* gA  = A  + (m0 + srow)*256 + schunk*8;
    const ushort* gB0 = Bw + (size_t)srow*256 + schunk*8;
    int chnk = (fg ^ (fr & 3)) * 8;

    f32x4 acc[4][4];
#pragma unroll
    for (int mt = 0; mt < 4; ++mt)
#pragma unroll
        for (int nt = 0; nt < 4; ++nt) acc[mt][nt] = (f32x4){0.f, 0.f, 0.f, 0.f};

    auto STAGE = [&](int buf, int ks) {
        int k0 = ks * 32;
        GLDS(gA + k0, &sA[buf][t*8]);
#pragma unroll
        for (int rr = 0; rr < 4; ++rr)
            GLDS(gB0 + rr*16384 + k0, &sB[buf][rr*2048 + t*8]);
    };

    STAGE(0, 0);
    __syncthreads();
    for (int ks = 0; ks < 8; ++ks) {
        int cur = ks & 1;
        if (ks < 7) STAGE(cur ^ 1, ks + 1);        // overlap with compute
        bf16x8 a[4], b[4];
#pragma unroll
        for (int mt = 0; mt < 4; ++mt)
            a[mt] = *(const bf16x8*)&sA[cur][(mt*16 + fr)*32 + chnk];
#pragma unroll
        for (int nt = 0; nt < 4; ++nt)
            b[nt] = *(const bf16x8*)&sB[cur][(w*64 + nt*16 + fr)*32 + chnk];
#pragma unroll
        for (int mt = 0; mt < 4; ++mt)
#pragma unroll
            for (int nt = 0; nt < 4; ++nt)
                acc[mt][nt] = __builtin_amdgcn_mfma_f32_16x16x32_bf16(
                    a[mt], b[nt], acc[mt][nt], 0, 0, 0);
        __syncthreads();                            // drains next-stage too
    }

    // epilogue: c-major tile in LDS (reuse sB, 32KB), then coalesced copy-out
    ushort* tile = &sB[0][0];                       // [64][256] ushort
    float biasv[4];
#pragma unroll
    for (int nt = 0; nt < 4; ++nt) biasv[nt] = bias[w*64 + fr + nt*16];
#pragma unroll
    for (int mt = 0; mt < 4; ++mt)
#pragma unroll
        for (int j = 0; j < 4; ++j) {
            int row = mt*16 + fg*4 + j;
#pragma unroll
            for (int nt = 0; nt < 4; ++nt) {
                float v = acc[mt][nt][j] + biasv[nt];
                tile[row*256 + (((fr + nt*16) << 2) | w)] = f2bf(v);
            }
        }
    __syncthreads();
    // dst: xVt[n][b][256] with n = m&4095, b = m>>12 (512B contiguous per row)
    int b0 = (int)(m0 >> 12), n0 = (int)(m0 & 4095);
    const int4* ts = (const int4*)tile;
    int4* td = (int4*)ob;
#pragma unroll
    for (int i = 0; i < 8; ++i) {
        int f = i*256 + t;                  // 0..2047
        int row = f >> 5, c16 = f & 31;
        td[(size_t)(n0 + row)*256 + b0*32 + c16] = ts[f];
    }
}

// ---------------------------------------------------------------------------
// K4: ONE WAVE per (n, 4-batch group). No max-subtraction (alpha bounded;
// e^a/sum e^a == reference's shifted form), so the only cross-lane
// reductions are one den-sum and one LN pass per wave. 4 independent
// b-streams give 4x ILP on every latency phase; xVt's [n][b][256] layout
// makes one edge's 4 stream reads span 2KB contiguous. Output out0 c-major
// per (b,n) row (k_mlp layout, unchanged).
__global__ __launch_bounds__(256) void k_agg_ln0(
        const float* __restrict__ alpha_t, const ushort* __restrict__ xVt,
        const int* __restrict__ offsets, const int* __restrict__ bucket_src,
        const float* __restrict__ att_r,
        const float* __restrict__ g0, const float* __restrict__ b0v,
        ushort* __restrict__ out0b) {
    __shared__ float4 s_w[4][64][4];        // 16KB: [wave][edge][stream]
    int t = threadIdx.x, wv = t >> 6, lane = t & 63;
    int gp = blockIdx.x * 4 + wv;           // 0..8191
    int n = gp >> 1, bh = (gp & 1) * 4;     // batches bh..bh+3
    int beg = offsets[n], end = offsets[n + 1];

    float4 acc[4], den[4];
#pragma unroll
    for (int s = 0; s < 4; ++s) {
        acc[s] = make_float4(0.f, 0.f, 0.f, 0.f);
        den[s] = make_float4(0.f, 0.f, 0.f, 0.f);
    }

    for (int chunk = beg; chunk < end; chunk += 64) {
        int cnt = min(64, end - chunk);
        int my_src = (lane < cnt) ? bucket_src[chunk + lane] : 0;
#pragma unroll
        for (int s = 0; s < 4; ++s) {
            float4 a4 = make_float4(NEG_INF_, NEG_INF_, NEG_INF_, NEG_INF_);
            if (lane < cnt) a4 = *(const float4*)&alpha_t[my_src*32 + (bh + s)*4];
            float4 ex;                       // exp(-inf) = 0 for idle lanes
            ex.x = __expf(a4.x); ex.y = __expf(a4.y);
            ex.z = __expf(a4.z); ex.w = __expf(a4.w);
            den[s].x += ex.x; den[s].y += ex.y; den[s].z += ex.z; den[s].w += ex.w;
            s_w[wv][lane][s] = ex;           // wave-private; no barrier
        }
        for (int e = 0; e < cnt; e += 4) {
#pragma unroll
            for (int k = 0; k < 4; ++k) {
                int srcn = __shfl(my_src, e + k);
                const ushort* vp = &xVt[(size_t)srcn*2048 + bh*256 + lane*4];
#pragma unroll
                for (int s = 0; s < 4; ++s) {
                    ushort4 v = *(const ushort4*)(vp + s*256);
                    float4 w4 = s_w[wv][e + k][s];
                    acc[s].x += w4.x * bf2f(v.x);
                    acc[s].y += w4.y * bf2f(v.y);
                    acc[s].z += w4.z * bf2f(v.z);
                    acc[s].w += w4.w * bf2f(v.w);
                }
            }
        }
    }

    // one den-sum reduction (4 streams x 4 comps, interleaved chains)
#pragma unroll
    for (int o = 32; o >= 1; o >>= 1)
#pragma unroll
        for (int s = 0; s < 4; ++s) {
            den[s].x += __shfl_xor(den[s].x, o);
            den[s].y += __shfl_xor(den[s].y, o);
            den[s].z += __shfl_xor(den[s].z, o);
            den[s].w += __shfl_xor(den[s].w, o);
        }

    float4 ar = make_float4(att_r[lane], att_r[64 + lane],
                            att_r[128 + lane], att_r[192 + lane]);
    float4 gv = make_float4(g0[lane], g0[64 + lane], g0[128 + lane], g0[192 + lane]);
    float4 bv = make_float4(b0v[lane], b0v[64 + lane], b0v[128 + lane], b0v[192 + lane]);

    float4 o4[4];
    float p1[4], p2[4];
#pragma unroll
    for (int s = 0; s < 4; ++s) {
        o4[s].x = acc[s].x / (den[s].x + 1e-16f) + ar.x;
        o4[s].y = acc[s].y / (den[s].y + 1e-16f) + ar.y;
        o4[s].z = acc[s].z / (den[s].z + 1e-16f) + ar.z;
        o4[s].w = acc[s].w / (den[s].w + 1e-16f) + ar.w;
        p1[s] = o4[s].x + o4[s].y + o4[s].z + o4[s].w;
        p2[s] = o4[s].x*o4[s].x + o4[s].y*o4[s].y + o4[s].z*o4[s].z + o4[s].w*o4[s].w;
    }
#pragma unroll
    for (int o = 32; o >= 1; o >>= 1)
#pragma unroll
        for (int s = 0; s < 4; ++s) {
            p1[s] += __shfl_xor(p1[s], o);
            p2[s] += __shfl_xor(p2[s], o);
        }
#pragma unroll
    for (int s = 0; s < 4; ++s) {
        float mean = p1[s] * (1.f/256.f);
        float inv = rsqrtf(p2[s] * (1.f/256.f) - mean*mean + 1e-5f);
        ushort4 st;
        st.x = f2bf((o4[s].x - mean) * inv * gv.x + bv.x);
        st.y = f2bf((o4[s].y - mean) * inv * gv.y + bv.y);
        st.z = f2bf((o4[s].z - mean) * inv * gv.z + bv.z);
        st.w = f2bf((o4[s].w - mean) * inv * gv.w + bv.w);
        *(ushort4*)&out0b[((size_t)(bh + s)*N_ + n)*256 + lane*4] = st;
    }
}

// ---------------------------------------------------------------------------
// K_MLP (fused, pipelined): full A-tile preloaded (16KB); W chunks
// double-buffered (2x16KB); Hs 16KB (row-XOR swizzle); red aliased on Hs;
// output staged in LDS (aliased on Bs) for coalesced f32 copy-out. 64KB LDS.
__global__ __launch_bounds__(256) void k_mlp(const ushort* __restrict__ Ain,
                                             const ushort* __restrict__ W1b,
                                             const float* __restrict__ b1,
                                             const ushort* __restrict__ W2b,
                                             const float* __restrict__ b2,
                                             const float* __restrict__ g,
                                             const float* __restrict__ bvec,
                                             float* __restrict__ out) {
    __shared__ __align__(16) ushort As[8192];       // 16KB persistent A tile
    __shared__ __align__(16) ushort Bs[2][8192];    // 32KB weight dbuf
    __shared__ __align__(16) ushort Hs[8192];       // 16KB hidden tile

    int t = threadIdx.x;
    int w = t >> 6, lane = t & 63;
    int fr = lane & 15, fg = lane >> 4;
    size_t m0 = (size_t)blockIdx.x * 32;

    int srow = t >> 2;
    int schunk = (t & 3) ^ (srow & 3);
    const ushort* gW1 = W1b + (size_t)srow*256 + schunk*8;
    const ushort* gW2 = W2b + (size_t)srow*256 + schunk*8;
    int chnk = (fg ^ (fr & 3)) * 8;

    auto stageW = [&](int buf, const ushort* gW, int ks) {
        int k0 = ks * 32;
#pragma unroll
        for (int rr = 0; rr < 4; ++rr)
            GLDS(gW + rr*16384 + k0, &Bs[buf][rr*2048 + t*8]);
    };

    // prologue: full A preload (4 passes) + W1 chunk 0
    {
        int row = (t >> 2) & 31, cs = t & 3, sc = cs ^ (row & 3);
#pragma unroll
        for (int p = 0; p < 4; ++p) {
            int ks = p*2 + (t >> 7);
            GLDS(Ain + (m0 + row)*256 + ks*32 + sc*8, &As[p*2048 + t*8]);
        }
    }
    stageW(0, gW1, 0);
    __syncthreads();

    // ---------------- GEMM1 ----------------
    f32x4 acc1[2][4];
#pragma unroll
    for (int mt = 0; mt < 2; ++mt)
#pragma unroll
        for (int nt = 0; nt < 4; ++nt) acc1[mt][nt] = (f32x4){0.f, 0.f, 0.f, 0.f};

    for (int ks = 0; ks < 8; ++ks) {
        int cur = ks & 1;
        if (ks < 7) stageW(cur ^ 1, gW1, ks + 1);
        bf16x8 a[2], b[4];
#pragma unroll
        for (int mt = 0; mt < 2; ++mt)
            a[mt] = *(const bf16x8*)&As[ks*1024 + (mt*16 + fr)*32 + chnk];
#pragma unroll
        for (int nt = 0; nt < 4; ++nt)
            b[nt] = *(const bf16x8*)&Bs[cur][(w*64 + nt*16 + fr)*32 + chnk];
#pragma unroll
        for (int mt = 0; mt < 2; ++mt)
#pragma unroll
            for (int nt = 0; nt < 4; ++nt)
                acc1[mt][nt] = __builtin_amdgcn_mfma_f32_16x16x32_bf16(
                    a[mt], b[nt], acc1[mt][nt], 0, 0, 0);
        __syncthreads();
    }

    // stage W2 chunk 0 early (Bs[0] free: last read at ks=6, sync'd)
    stageW(0, gW2, 0);

    // epilogue1: Hs = relu(acc1 + b1), row-XOR swizzled
    int colb = w*64 + fr;
    {
        float b1v[4];
#pragma unroll
        for (int nt = 0; nt < 4; ++nt) b1v[nt] = b1[colb + nt*16];
#pragma unroll
        for (int mt = 0; mt < 2; ++mt)
#pragma unroll
            for (int j = 0; j < 4; ++j) {
                int row = mt*16 + fg*4 + j;
#pragma unroll
                for (int nt = 0; nt < 4; ++nt) {
                    float v = fmaxf(acc1[mt][nt][j] + b1v[nt], 0.f);
                    int byteoff = (row*512 + (colb + nt*16)*2) ^ ((row & 7) << 4);
                    *(ushort*)((char*)Hs + byteoff) = f2bf(v);
                }
            }
    }
    __syncthreads();                         // Hs visible + W2 ks0 drained

    // ---------------- GEMM2 ----------------
    f32x4 acc2[2][4];
#pragma unroll
    for (int mt = 0; mt < 2; ++mt)
#pragma unroll
        for (int nt = 0; nt < 4; ++nt) acc2[mt][nt] = (f32x4){0.f, 0.f, 0.f, 0.f};

    for (int ks = 0; ks < 8; ++ks) {
        int cur = ks & 1;
        if (ks < 7) stageW(cur ^ 1, gW2, ks + 1);
        int k0 = ks * 32;
        bf16x8 a[2], b[4];
#pragma unroll
        for (int mt = 0; mt < 2; ++mt) {
            int row = mt*16 + fr;
            int byteoff = (row*512 + (k0 + fg*8)*2) ^ ((row & 7) << 4);
            a[mt] = *(const bf16x8*)((char*)Hs + byteoff);
        }
#pragma unroll
        for (int nt = 0; nt < 4; ++nt)
            b[nt] = *(const bf16x8*)&Bs[cur][(w*64 + nt*16 + fr)*32 + chnk];
#pragma unroll
        for (int mt = 0; mt < 2; ++mt)
#pragma unroll
            for (int nt = 0; nt < 4; ++nt)
                acc2[mt][nt] = __builtin_amdgcn_mfma_f32_16x16x32_bf16(
                    a[mt], b[nt], acc2[mt][nt], 0, 0, 0);
        __syncthreads();
    }

    // epilogue2: residual (from As) + LN1; red aliased on Hs (free now)
    float2 (*red)[4] = (float2(*)[4])Hs;
    float b2v[4], gv[4], bvv[4];
#pragma unroll
    for (int nt = 0; nt < 4; ++nt) {
        b2v[nt] = b2[colb + nt*16];
        gv[nt]  = g[colb + nt*16];
        bvv[nt] = bvec[colb + nt*16];
    }
#pragma unroll
    for (int mt = 0; mt < 2; ++mt)
#pragma unroll
        for (int j = 0; j < 4; ++j) {
            int row = mt*16 + fg*4 + j;
            float p1 = 0.f, p2 = 0.f;
#pragma unroll
            for (int nt = 0; nt < 4; ++nt) {
                float v = fmaxf(acc2[mt][nt][j] + b2v[nt], 0.f);
                int kp  = ((nt*16 + fr) << 2) | w;        // res c-major index
                int ks2 = kp >> 5, off = kp & 31;
                int idx = ks2*1024 + row*32 + ((off >> 3) ^ (row & 3))*8 + (off & 7);
                float y = bf2f(As[idx]) + v;
                acc2[mt][nt][j] = y;
                p1 += y; p2 += y*y;
            }
#pragma unroll
            for (int o = 8; o >= 1; o >>= 1) { p1 += __shfl_xor(p1, o); p2 += __shfl_xor(p2, o); }
            if (fr == 0) red[row][w] = make_float2(p1, p2);
        }
    __syncthreads();

    // LN + stage f32 tile in LDS (alias Bs, 32KB) for coalesced copy-out
    float* tileF = (float*)&Bs[0][0];               // [32][256] f32
#pragma unroll
    for (int mt = 0; mt < 2; ++mt)
#pragma unroll
        for (int j = 0; j < 4; ++j) {
            int row = mt*16 + fg*4 + j;
            float2 s0 = red[row][0], sA2 = red[row][1], sB2 = red[row][2], sC = red[row][3];
            float s = s0.x + sA2.x + sB2.x + sC.x;
            float q = s0.y + sA2.y + sB2.y + sC.y;
            float mean = s * (1.f/256.f);
            float inv = rsqrtf(q * (1.f/256.f) - mean*mean + 1e-5f);
#pragma unroll
            for (int nt = 0; nt < 4; ++nt)
                tileF[row*256 + colb + nt*16] =
                    (acc2[mt][nt][j] - mean) * inv * gv[nt] + bvv[nt];
        }
    __syncthreads();
    const int4* ts = (const int4*)tileF;
    int4* td = (int4*)(out + m0*256);               // 32KB contiguous
#pragma unroll
    for (int i = 0; i < 8; ++i) td[i*256 + t] = ts[i*256 + t];
}

// ---------------------------------------------------------------------------
extern "C" void kernel_launch(void* const* d_in, const int* in_sizes, int n_in,
                              void* d_out, int out_size, void* d_ws, size_t ws_size,
                              hipStream_t stream) {
    const float* x     = (const float*)d_in[0];
    const int*   ei    = (const int*)  d_in[1];
    const float* W_K   = (const float*)d_in[2];
    const float* b_K   = (const float*)d_in[3];
    const float* W_V   = (const float*)d_in[4];
    const float* b_V   = (const float*)d_in[5];
    const float* att_r = (const float*)d_in[6];
    const float* ln0_g = (const float*)d_in[7];
    const float* ln0_b = (const float*)d_in[8];
    const float* ln1_g = (const float*)d_in[9];
    const float* ln1_b = (const float*)d_in[10];
    const float* W1    = (const float*)d_in[11];
    const float* b1    = (const float*)d_in[12];
    const float* W2    = (const float*)d_in[13];
    const float* b2    = (const float*)d_in[14];
    float* out = (float*)d_out;

    // workspace layout (bytes). Buffer roles:
    //   bufA: x_bf16 (k_alpha) -> read by k_g0f -> overwritten by agg's out0
    //   bufB: xVt [n][b][256] (k_g0f output) -> read by agg
    char* wsb = (char*)d_ws;
    float*  u     = (float*) (wsb);                 // 4KB
    float*  cvec  = (float*) (wsb + 4096);          // pad 4KB
    float*  alpha = (float*) (wsb + 8192);          // 512KB ([n][b][h])
    ushort* WVb   = (ushort*)(wsb + 532480);        // 128KB
    ushort* W1b   = WVb + 65536;                    // 128KB (k-permuted)
    ushort* W2b   = W1b + 65536;                    // 128KB
    int*    ints  = (int*)  (W2b + 65536);
    int* counts   = ints;                           // 4096
    int* cursor   = ints + 4096;                    // 4096
    int* offsets  = ints + 8192;                    // 4097 (pad)
    int* bucket   = ints + 12544;                   // 32768
    ushort* bufA  = (ushort*)(wsb + 1114112);       // 16MB
    ushort* bufB  = bufA + 8388608;                 // 16MB
    size_t need   = 1114112 + 2ull*16777216;        // ~33.1 MB

    if (ws_size < need) return;   // clean fail, no OOB

    hipMemsetAsync(counts, 0, 8192 * sizeof(int), stream);   // counts + cursor

    k_setup  <<<324, 256, 0, stream>>>(W_K, b_K, att_r, u, cvec,
                                       W_V, W1, W2, WVb, W1b, W2b, ei, counts);
    k_alpha  <<<ROWS_/4, 256, 0, stream>>>(x, u, cvec, alpha, bufA);
    k_scan   <<<1, 256, 0, stream>>>(counts, offsets);
    k_g0f    <<<640, 256, 0, stream>>>(bufA, WVb, b_V, bufB,
                                       ei, offsets, cursor, bucket);
    k_agg_ln0<<<2048, 256, 0, stream>>>(alpha, bufB, offsets, bucket,
                                        att_r, ln0_g, ln0_b, bufA);
    k_mlp    <<<ROWS_/32, 256, 0, stream>>>(bufA, W1b, b1, W2b, b2,
                                            ln1_g, ln1_b, out);
}